// Round 13
// baseline (363.238 us; speedup 1.0000x reference)
//
#include <hip/hip_runtime.h>
#include <math.h>

#define BB 8
#define CC 64
#define OO 64
#define HH 128
#define WW 128
#define PP 9
#define HWIMG 16384           // H*W per batch
#define NTOT  131072          // B*H*W

typedef __attribute__((ext_vector_type(8))) _Float16 h8;
typedef __attribute__((ext_vector_type(2))) _Float16 h2;
typedef __attribute__((ext_vector_type(4))) float f32x4;

// ---------------------------------------------------------------------------
// Kernel 0: prep. blocks 0..143: wtf[p][o][c] f16. block 144: dwt[tap][c],
// bnA[c]=gamma*rsqrt(var+eps), bnB[c]=(dw_b-mean)*bnA+beta.
// ---------------------------------------------------------------------------
__global__ void k_prep(const float* __restrict__ w,
                       const float* __restrict__ dw_w,
                       const float* __restrict__ dw_b,
                       const float* __restrict__ gamma,
                       const float* __restrict__ beta,
                       const float* __restrict__ mean,
                       const float* __restrict__ var,
                       _Float16* __restrict__ wtf,
                       float* __restrict__ dwt,
                       float* __restrict__ bnA,
                       float* __restrict__ bnB) {
  int bid = blockIdx.x, t = threadIdx.x;
  if (bid < 144) {
    int i = bid * 256 + t;
    int c = i & 63, o = (i >> 6) & 63, p = i >> 12;
    wtf[i] = (_Float16)w[(o * 64 + c) * 9 + p];
  } else {
    if (t < 64) {
      float A = gamma[t] * rsqrtf(var[t] + 1e-5f);
      bnA[t] = A;
      bnB[t] = (dw_b[t] - mean[t]) * A + beta[t];
    }
    for (int i = t; i < 576; i += 256) {
      int tap = i % 9, c = i / 9;
      dwt[tap * 64 + c] = dw_w[c * 9 + tap];
    }
  }
}

// ---------------------------------------------------------------------------
// Kernel 1: x NCHW f32 -> xt[b][pix][c] f16 (NHWC) (verbatim, known good)
// ---------------------------------------------------------------------------
__global__ void __launch_bounds__(256, 4)
k_tr(const float* __restrict__ x, _Float16* __restrict__ xt) {
  __shared__ _Float16 lt[64][66];
  int bid = blockIdx.x;
  int vbid = (bid & 7) * 256 + (bid >> 3);    // XCD k <- batch k
  int tid = threadIdx.x;
  int wid = tid >> 6, ln = tid & 63;
  int b = vbid >> 8;
  int pix0 = (vbid & 255) * 64;
  const float* xbb = x + (size_t)b * CC * HWIMG;

  #pragma unroll
  for (int i = 0; i < 8; ++i) {
    int c0 = (wid * 8 + i) * 2;
    float v0 = xbb[(size_t)c0 * HWIMG + pix0 + ln];
    float v1 = xbb[(size_t)(c0 + 1) * HWIMG + pix0 + ln];
    h2 hv;
    hv[0] = (_Float16)v0;
    hv[1] = (_Float16)v1;
    *(h2*)&lt[ln][c0] = hv;
  }
  __syncthreads();

  int pq = tid >> 2, q = tid & 3;
  h8 o0, o1;
  #pragma unroll
  for (int j = 0; j < 4; ++j) {
    h2 v = *(h2*)&lt[pq][q * 16 + 2 * j];
    o0[2 * j] = v[0];
    o0[2 * j + 1] = v[1];
  }
  #pragma unroll
  for (int j = 0; j < 4; ++j) {
    h2 v = *(h2*)&lt[pq][q * 16 + 8 + 2 * j];
    o1[2 * j] = v[0];
    o1[2 * j + 1] = v[1];
  }
  _Float16* op = xt + ((size_t)((b << 14) + pix0 + pq)) * 64 + q * 16;
  *(h8*)op = o0;
  *(h8*)(op + 8) = o1;
}

// ---------------------------------------------------------------------------
// Kernel 2: FUSED offsets + gather + MFMA. 8x16 px tile, halo ±2 = 12x20
// records in LDS (staged once, clamped, chunk-swizzled).
//   Phase 1: thread (wid, lm, lk) computes, for its 2 pixels, the dwconv+BN+
//     SiLU over its 16 channels (chunks lk and lk+4) from the SAME halo
//     (per-tap validity zeroing reproduces conv zero-padding), then the 18
//     1x1 dots via 4-lane shfl_xor(16/32) reduce -> syr/sxr[9][2] in regs.
//   Phase 2: champion gather+MFMA loop, byte-identical math.
// ---------------------------------------------------------------------------
__global__ void __launch_bounds__(256, 4)
k_fused(const _Float16* __restrict__ xt,
        const float* __restrict__ dwt,
        const float* __restrict__ bnA,
        const float* __restrict__ bnB,
        const float* __restrict__ pw_w,
        const float* __restrict__ pw_b,
        const _Float16* __restrict__ wtf,
        const float* __restrict__ bias,
        float* __restrict__ out) {
  __shared__ __attribute__((aligned(16))) char smem[240 * 128];
  int bid = blockIdx.x;
  int b = bid & 7, t = bid >> 3;            // XCD k <- batch k; 128 tiles/img
  int ty0 = (t >> 3) * 8, tx0 = (t & 7) * 16;
  int tid = threadIdx.x, wid = tid >> 6, ln = tid & 63;
  int lm = ln & 15, lk = ln >> 4;
  const _Float16* xb = xt + (((size_t)b) << 14) * 64;

  // ---- stage 12x20 halo records (row/col-clamped), chunk-swizzled
  for (int ch = tid; ch < 1920; ch += 256) {
    int rec = ch >> 3, j = ch & 7;
    int ry = rec / 20, rx = rec - ry * 20;
    int yy = min(max(ty0 - 2 + ry, 0), HH - 1);
    int xx = min(max(tx0 - 2 + rx, 0), WW - 1);
    h8 v = *((const h8*)(xb + ((size_t)((yy << 7) + xx)) * 64) + (j ^ (rec & 7)));
    *(h8*)(smem + rec * 128 + j * 16) = v;
  }
  __syncthreads();

  int y0r = ty0 + wid * 2;        // this thread's 2 pixel rows: y0r, y0r+1
  int xcol = tx0 + lm;

  // ======== Phase 1: offsets ========
  // s[nt][0..7] = chunk lk (ch lk*8..+7), s[nt][8..15] = chunk lk+4 (ch 32+lk*8..+7)
  float s0[16], s1[16];
  #pragma unroll
  for (int e = 0; e < 16; ++e) { s0[e] = 0.f; s1[e] = 0.f; }

  #pragma unroll
  for (int tap = 0; tap < 9; ++tap) {
    int dy = tap / 3 - 1, dx = tap % 3 - 1;
    int xx = xcol + dx;
    bool okx = (xx >= 0) & (xx < WW);
    const float* dwp = dwt + tap * 64;
    f32x4 d0a = *(const f32x4*)(dwp + lk * 8);
    f32x4 d0b = *(const f32x4*)(dwp + lk * 8 + 4);
    f32x4 d1a = *(const f32x4*)(dwp + 32 + lk * 8);
    f32x4 d1b = *(const f32x4*)(dwp + 32 + lk * 8 + 4);
    #pragma unroll
    for (int nt = 0; nt < 2; ++nt) {
      int qy = wid * 2 + nt;
      int yy = ty0 + qy + dy;
      bool ok = okx & (yy >= 0) & (yy < HH);
      int rec = (qy + dy + 2) * 20 + (lm + dx + 2);
      h8 v0 = *(const h8*)(smem + rec * 128 + (((lk    ) ^ (rec & 7)) << 4));
      h8 v1 = *(const h8*)(smem + rec * 128 + (((lk + 4) ^ (rec & 7)) << 4));
      if (!ok) { v0 = (h8)(_Float16)0.f; v1 = (h8)(_Float16)0.f; }
      float* s = nt ? s1 : s0;
      #pragma unroll
      for (int e = 0; e < 4; ++e) {
        s[e]      += d0a[e] * (float)v0[e];
        s[4 + e]  += d0b[e] * (float)v0[4 + e];
        s[8 + e]  += d1a[e] * (float)v1[e];
        s[12 + e] += d1b[e] * (float)v1[4 + e];
      }
    }
  }

  // BN + SiLU (this lane's 16 channels)
  {
    f32x4 a0 = *(const f32x4*)(bnA + lk * 8);
    f32x4 a1 = *(const f32x4*)(bnA + lk * 8 + 4);
    f32x4 a2 = *(const f32x4*)(bnA + 32 + lk * 8);
    f32x4 a3 = *(const f32x4*)(bnA + 32 + lk * 8 + 4);
    f32x4 b0 = *(const f32x4*)(bnB + lk * 8);
    f32x4 b1 = *(const f32x4*)(bnB + lk * 8 + 4);
    f32x4 b2 = *(const f32x4*)(bnB + 32 + lk * 8);
    f32x4 b3 = *(const f32x4*)(bnB + 32 + lk * 8 + 4);
    #pragma unroll
    for (int nt = 0; nt < 2; ++nt) {
      float* s = nt ? s1 : s0;
      #pragma unroll
      for (int e = 0; e < 4; ++e) {
        float v;
        v = s[e]      * a0[e] + b0[e]; s[e]      = v / (1.f + __expf(-v));
        v = s[4 + e]  * a1[e] + b1[e]; s[4 + e]  = v / (1.f + __expf(-v));
        v = s[8 + e]  * a2[e] + b2[e]; s[8 + e]  = v / (1.f + __expf(-v));
        v = s[12 + e] * a3[e] + b3[e]; s[12 + e] = v / (1.f + __expf(-v));
      }
    }
  }

  // 1x1 conv -> syr/sxr directly. Partial dot over 16 ch, reduce across the
  // 4 lk-lanes (same lm) with shfl_xor 16 and 32.
  float syr[PP][2], sxr[PP][2];
  float fx = (float)xcol;
  #pragma unroll
  for (int p = 0; p < PP; ++p) {
    #pragma unroll
    for (int d = 0; d < 2; ++d) {
      int k = 2 * p + d;
      const float* pwp = pw_w + k * CC;
      f32x4 p0 = *(const f32x4*)(pwp + lk * 8);
      f32x4 p1 = *(const f32x4*)(pwp + lk * 8 + 4);
      f32x4 p2 = *(const f32x4*)(pwp + 32 + lk * 8);
      f32x4 p3 = *(const f32x4*)(pwp + 32 + lk * 8 + 4);
      #pragma unroll
      for (int nt = 0; nt < 2; ++nt) {
        const float* s = nt ? s1 : s0;
        float a = 0.f;
        #pragma unroll
        for (int e = 0; e < 4; ++e) {
          a += p0[e] * s[e];
          a += p1[e] * s[4 + e];
          a += p2[e] * s[8 + e];
          a += p3[e] * s[12 + e];
        }
        a += __shfl_xor(a, 16);
        a += __shfl_xor(a, 32);
        a += pw_b[k];
        if (d == 0) syr[p][nt] = (float)(y0r + nt) + a + (float)(p / 3 - 1);
        else        sxr[p][nt] = fx + a + (float)(p % 3 - 1);
      }
    }
  }

  // ======== Phase 2: gather + MFMA (champion body, verbatim math) ========
  f32x4 acc[4][2];     // [mt][nt]
  #pragma unroll
  for (int mt = 0; mt < 4; ++mt)
    #pragma unroll
    for (int nt = 0; nt < 2; ++nt) acc[mt][nt] = (f32x4){0.f, 0.f, 0.f, 0.f};

  const _Float16* wl = wtf + lm * 64 + lk * 8;   // + p*4096 + mt*1024 + kc*32

  #pragma unroll
  for (int p = 0; p < PP; ++p) {
    h8 bfr[2][2];
    #pragma unroll
    for (int nt = 0; nt < 2; ++nt) {
      float sy = syr[p][nt], sx = sxr[p][nt];
      float y0f = floorf(sy), x0f = floorf(sx);
      float wy1 = sy - y0f, wy0 = 1.f - wy1;
      float wx1 = sx - x0f, wx0 = 1.f - wx1;
      int y0 = (int)y0f, x0i = (int)x0f;
      bool vy0 = (y0 >= 0) & (y0 < HH);
      bool vy1 = (y0 + 1 >= 0) & (y0 + 1 < HH);
      bool vx0 = (x0i >= 0) & (x0i < WW);
      bool vx1 = (x0i + 1 >= 0) & (x0i + 1 < WW);
      float w00 = (vy0 && vx0) ? wy0 * wx0 : 0.f;
      float w01 = (vy0 && vx1) ? wy0 * wx1 : 0.f;
      float w10 = (vy1 && vx0) ? wy1 * wx0 : 0.f;
      float w11 = (vy1 && vx1) ? wy1 * wx1 : 0.f;

      int iy0 = min(max(y0 - ty0 + 2, 0), 11);
      int iy1 = min(max(y0 + 1 - ty0 + 2, 0), 11);
      int ix0 = min(max(x0i - tx0 + 2, 0), 19);
      int ix1 = min(max(x0i + 1 - tx0 + 2, 0), 19);
      int r00 = iy0 * 20 + ix0, r01 = iy0 * 20 + ix1;
      int r10 = iy1 * 20 + ix0, r11 = iy1 * 20 + ix1;

      h8 v00a = *(const h8*)(smem + r00 * 128 + (((lk    ) ^ (r00 & 7)) << 4));
      h8 v00b = *(const h8*)(smem + r00 * 128 + (((lk + 4) ^ (r00 & 7)) << 4));
      h8 v01a = *(const h8*)(smem + r01 * 128 + (((lk    ) ^ (r01 & 7)) << 4));
      h8 v01b = *(const h8*)(smem + r01 * 128 + (((lk + 4) ^ (r01 & 7)) << 4));
      h8 v10a = *(const h8*)(smem + r10 * 128 + (((lk    ) ^ (r10 & 7)) << 4));
      h8 v10b = *(const h8*)(smem + r10 * 128 + (((lk + 4) ^ (r10 & 7)) << 4));
      h8 v11a = *(const h8*)(smem + r11 * 128 + (((lk    ) ^ (r11 & 7)) << 4));
      h8 v11b = *(const h8*)(smem + r11 * 128 + (((lk + 4) ^ (r11 & 7)) << 4));

      h8 w00v = (h8)(_Float16)w00;
      h8 w01v = (h8)(_Float16)w01;
      h8 w10v = (h8)(_Float16)w10;
      h8 w11v = (h8)(_Float16)w11;
      bfr[nt][0] = v00a * w00v + v01a * w01v + v10a * w10v + v11a * w11v;
      bfr[nt][1] = v00b * w00v + v01b * w01v + v10b * w10v + v11b * w11v;
    }

    #pragma unroll
    for (int mt = 0; mt < 4; ++mt) {
      h8 a0 = *(const h8*)(wl + p * 4096 + mt * 1024);
      h8 a1 = *(const h8*)(wl + p * 4096 + mt * 1024 + 32);
      #pragma unroll
      for (int nt = 0; nt < 2; ++nt) {
        acc[mt][nt] = __builtin_amdgcn_mfma_f32_16x16x32_f16(a0, bfr[nt][0], acc[mt][nt], 0, 0, 0);
        acc[mt][nt] = __builtin_amdgcn_mfma_f32_16x16x32_f16(a1, bfr[nt][1], acc[mt][nt], 0, 0, 0);
      }
    }
  }

  // ---- epilogue: C/D layout col=lane&15 (pixel), row=(lane>>4)*4+reg (m)
  #pragma unroll
  for (int nt = 0; nt < 2; ++nt) {
    int pix = ((y0r + nt) << 7) + tx0 + lm;
    #pragma unroll
    for (int mt = 0; mt < 4; ++mt) {
      #pragma unroll
      for (int r = 0; r < 4; ++r) {
        int m = mt * 16 + lk * 4 + r;
        out[((size_t)b * OO + m) * HWIMG + pix] = acc[mt][nt][r] + bias[m];
      }
    }
  }
}

// ---------------------------------------------------------------------------
extern "C" void kernel_launch(void* const* d_in, const int* in_sizes, int n_in,
                              void* d_out, int out_size, void* d_ws, size_t ws_size,
                              hipStream_t stream) {
  const float* x        = (const float*)d_in[0];
  const float* dw_w     = (const float*)d_in[1];
  const float* dw_b     = (const float*)d_in[2];
  const float* bn_gamma = (const float*)d_in[3];
  const float* bn_beta  = (const float*)d_in[4];
  const float* bn_mean  = (const float*)d_in[5];
  const float* bn_var   = (const float*)d_in[6];
  const float* pw_w     = (const float*)d_in[7];
  const float* pw_b     = (const float*)d_in[8];
  const float* weight   = (const float*)d_in[9];
  const float* bias     = (const float*)d_in[10];
  float* out = (float*)d_out;

  char* ws = (char*)d_ws;
  _Float16* wtf = (_Float16*)ws;                               // 73728 B
  size_t o1 = (size_t)PP * OO * CC * 2;
  _Float16* xtb = (_Float16*)(ws + o1);                        // 16.8 MB
  size_t o2 = o1 + (size_t)NTOT * CC * 2;
  float* dwt = (float*)(ws + o2);                              // 2304 B
  float* bnA = (float*)(ws + o2 + 2304);
  float* bnB = (float*)(ws + o2 + 2304 + 256);

  k_prep<<<145, 256, 0, stream>>>(weight, dw_w, dw_b, bn_gamma, bn_beta,
                                  bn_mean, bn_var, wtf, dwt, bnA, bnB);
  k_tr<<<NTOT / 64, 256, 0, stream>>>(x, xtb);
  k_fused<<<NTOT / 128, 256, 0, stream>>>(xtb, dwt, bnA, bnB, pw_w, pw_b,
                                          wtf, bias, out);
}

// Round 14
// 77.101 us; speedup vs baseline: 4.7112x; 4.7112x over previous
//
#include <hip/hip_runtime.h>
#include <math.h>

#define BB 8
#define CC 64
#define OO 64
#define HH 128
#define WW 128
#define PP 9
#define HWIMG 16384           // H*W per batch
#define NTOT  131072          // B*H*W

typedef __attribute__((ext_vector_type(8))) _Float16 h8;
typedef __attribute__((ext_vector_type(2))) _Float16 h2;
typedef __attribute__((ext_vector_type(4))) float f32x4;

// ---------------------------------------------------------------------------
// Kernel 0: prep. blocks 0..143: wtf2 in per-lane-coalesced layout:
//   linear i: e=i&7, ln=(i>>3)&63, kc=(i>>9)&1, mt=(i>>10)&3, p=i>>12
//   value = w[o=mt*16+(ln&15)][c=kc*32+(ln>>4)*8+e][p]
// block 144: dwt[tap][c], bnA[c], bnB[c].
// ---------------------------------------------------------------------------
__global__ void k_prep(const float* __restrict__ w,
                       const float* __restrict__ dw_w,
                       const float* __restrict__ dw_b,
                       const float* __restrict__ gamma,
                       const float* __restrict__ beta,
                       const float* __restrict__ mean,
                       const float* __restrict__ var,
                       _Float16* __restrict__ wtf2,
                       float* __restrict__ dwt,
                       float* __restrict__ bnA,
                       float* __restrict__ bnB) {
  int bid = blockIdx.x, t = threadIdx.x;
  if (bid < 144) {
    int i = bid * 256 + t;
    int e  = i & 7;
    int ln = (i >> 3) & 63;
    int kc = (i >> 9) & 1;
    int mt = (i >> 10) & 3;
    int p  = i >> 12;
    int o = mt * 16 + (ln & 15);
    int c = kc * 32 + (ln >> 4) * 8 + e;
    wtf2[i] = (_Float16)w[(o * 64 + c) * 9 + p];
  } else {
    if (t < 64) {
      float A = gamma[t] * rsqrtf(var[t] + 1e-5f);
      bnA[t] = A;
      bnB[t] = (dw_b[t] - mean[t]) * A + beta[t];
    }
    for (int i = t; i < 576; i += 256) {
      int tap = i % 9, c = i / 9;
      dwt[tap * 64 + c] = dw_w[c * 9 + tap];
    }
  }
}

// ---------------------------------------------------------------------------
// Kernel 1: x NCHW f32 -> xt[b][pix][c] f16 (NHWC) (verbatim, known good)
// ---------------------------------------------------------------------------
__global__ void __launch_bounds__(256, 4)
k_tr(const float* __restrict__ x, _Float16* __restrict__ xt) {
  __shared__ _Float16 lt[64][66];
  int bid = blockIdx.x;
  int vbid = (bid & 7) * 256 + (bid >> 3);    // XCD k <- batch k
  int tid = threadIdx.x;
  int wid = tid >> 6, ln = tid & 63;
  int b = vbid >> 8;
  int pix0 = (vbid & 255) * 64;
  const float* xbb = x + (size_t)b * CC * HWIMG;

  #pragma unroll
  for (int i = 0; i < 8; ++i) {
    int c0 = (wid * 8 + i) * 2;
    float v0 = xbb[(size_t)c0 * HWIMG + pix0 + ln];
    float v1 = xbb[(size_t)(c0 + 1) * HWIMG + pix0 + ln];
    h2 hv;
    hv[0] = (_Float16)v0;
    hv[1] = (_Float16)v1;
    *(h2*)&lt[ln][c0] = hv;
  }
  __syncthreads();

  int pq = tid >> 2, q = tid & 3;
  h8 o0, o1;
  #pragma unroll
  for (int j = 0; j < 4; ++j) {
    h2 v = *(h2*)&lt[pq][q * 16 + 2 * j];
    o0[2 * j] = v[0];
    o0[2 * j + 1] = v[1];
  }
  #pragma unroll
  for (int j = 0; j < 4; ++j) {
    h2 v = *(h2*)&lt[pq][q * 16 + 8 + 2 * j];
    o1[2 * j] = v[0];
    o1[2 * j + 1] = v[1];
  }
  _Float16* op = xt + ((size_t)((b << 14) + pix0 + pq)) * 64 + q * 16;
  *(h8*)op = o0;
  *(h8*)(op + 8) = o1;
}

// ---------------------------------------------------------------------------
// Kernel 2: offsets (r12 body — 512 thr, intra-wave channel-split, f32x4
// filter loads; verified). Plane-format soff stores.
// ---------------------------------------------------------------------------
__global__ void __launch_bounds__(512, 2)
k_off2(const _Float16* __restrict__ xt,
       const float* __restrict__ dwt,
       const float* __restrict__ bnA,
       const float* __restrict__ bnB,
       const float* __restrict__ pw_w,
       const float* __restrict__ pw_b,
       float* __restrict__ soff) {
  __shared__ __attribute__((aligned(16))) char lsm[324 * 128];
  int bid = blockIdx.x;
  int b = bid & 7, t = bid >> 3;           // XCD k <- batch k
  int ty0 = (t >> 3) * 16, tx0 = (t & 7) * 16;
  int tid = threadIdx.x;
  const _Float16* xb = xt + (((size_t)b) << 14) * 64;

  for (int ch = tid; ch < 2592; ch += 512) {
    int rec = ch >> 3, j = ch & 7;
    int ry = rec / 18, rx = rec - ry * 18;
    int yy = ty0 - 1 + ry, xx = tx0 - 1 + rx;
    bool in = (yy >= 0) & (yy < HH) & (xx >= 0) & (xx < WW);
    h8 v = (h8)(_Float16)0.f;
    if (in) v = *((const h8*)(xb + ((size_t)((yy << 7) + xx)) * 64) + (j ^ (rec & 7)));
    *(h8*)(lsm + rec * 128 + j * 16) = v;
  }
  __syncthreads();

  int wv = tid >> 6, ln = tid & 63;
  int px = wv * 32 + (ln & 31);        // 8 waves x 32 px = 256 px
  int chalf = ln >> 5;                 // 0: ch 0..31, 1: ch 32..63
  int qy = px >> 4, qx = px & 15;

  float s[32];
  #pragma unroll
  for (int c = 0; c < 32; ++c) s[c] = 0.f;

  #pragma unroll
  for (int tap = 0; tap < 9; ++tap) {
    int dy = tap / 3 - 1, dx = tap % 3 - 1;
    int rec = (qy + dy + 1) * 18 + (qx + dx + 1);
    const f32x4* dwp4 = (const f32x4*)(dwt + tap * 64 + chalf * 32);
    #pragma unroll
    for (int gq = 0; gq < 4; ++gq) {
      int g = chalf * 4 + gq;
      h8 v = *(const h8*)(lsm + rec * 128 + ((g ^ (rec & 7)) << 4));
      f32x4 d0 = dwp4[gq * 2];
      f32x4 d1 = dwp4[gq * 2 + 1];
      #pragma unroll
      for (int e = 0; e < 4; ++e) s[gq * 8 + e]     += d0[e] * (float)v[e];
      #pragma unroll
      for (int e = 0; e < 4; ++e) s[gq * 8 + 4 + e] += d1[e] * (float)v[4 + e];
    }
  }

  {
    const f32x4* bnA4 = (const f32x4*)(bnA + chalf * 32);
    const f32x4* bnB4 = (const f32x4*)(bnB + chalf * 32);
    #pragma unroll
    for (int q = 0; q < 8; ++q) {
      f32x4 a4 = bnA4[q];
      f32x4 b4 = bnB4[q];
      #pragma unroll
      for (int e = 0; e < 4; ++e) {
        float v = s[q * 4 + e] * a4[e] + b4[e];
        s[q * 4 + e] = v / (1.f + __expf(-v));
      }
    }
  }

  float off[2 * PP];
  #pragma unroll
  for (int k = 0; k < 2 * PP; ++k) {
    const f32x4* pwp4 = (const f32x4*)(pw_w + k * CC + chalf * 32);
    float a = 0.f;
    #pragma unroll
    for (int j = 0; j < 8; ++j) {
      f32x4 pv = pwp4[j];
      a += pv[0] * s[4 * j];
      a += pv[1] * s[4 * j + 1];
      a += pv[2] * s[4 * j + 2];
      a += pv[3] * s[4 * j + 3];
    }
    off[k] = a + __shfl_xor(a, 32) + pw_b[k];
  }

  if (chalf == 0) {
    int y = ty0 + qy, xw = tx0 + qx;
    size_t idx = (size_t)(b << 14) + (y << 7) + xw;
    float fy = (float)y, fx = (float)xw;
    #pragma unroll
    for (int p = 0; p < PP; ++p) {
      soff[(size_t)(2 * p) * NTOT + idx]     = fy + off[2 * p]     + (float)(p / 3 - 1);
      soff[(size_t)(2 * p + 1) * NTOT + idx] = fx + off[2 * p + 1] + (float)(p % 3 - 1);
    }
  }
}

// ---------------------------------------------------------------------------
// Kernel 3: gather+MFMA (champion r6/r11 body; ONLY the A-frag addressing
// changed to the coalesced wtf2 layout: lane ln reads base + ln*16B).
// ---------------------------------------------------------------------------
__global__ void __launch_bounds__(256, 4)
k_main(const _Float16* __restrict__ xt,
       const float* __restrict__ soff,
       const _Float16* __restrict__ wtf2,
       const float* __restrict__ bias,
       float* __restrict__ out) {
  __shared__ __attribute__((aligned(16))) char smem[240 * 128];
  int bid = blockIdx.x;
  int b = bid & 7, t = bid >> 3;            // XCD k <- batch k; 128 tiles/img
  int ty0 = (t >> 3) * 8, tx0 = (t & 7) * 16;
  int tid = threadIdx.x, wid = tid >> 6, ln = tid & 63;
  int lm = ln & 15, lk = ln >> 4;
  const _Float16* xb = xt + (((size_t)b) << 14) * 64;

  // ---- preload ALL soff for this thread's 2 pixels (issued before staging)
  int y0r = ty0 + wid * 2;
  int ng0 = (b << 14) + (y0r << 7) + tx0 + lm;
  float syr[PP][2], sxr[PP][2];
  #pragma unroll
  for (int p = 0; p < PP; ++p) {
    syr[p][0] = soff[(size_t)(2 * p) * NTOT + ng0];
    syr[p][1] = soff[(size_t)(2 * p) * NTOT + ng0 + 128];
    sxr[p][0] = soff[(size_t)(2 * p + 1) * NTOT + ng0];
    sxr[p][1] = soff[(size_t)(2 * p + 1) * NTOT + ng0 + 128];
  }

  // ---- stage 12x20 halo records (row/col-clamped), chunk-swizzled
  for (int ch = tid; ch < 1920; ch += 256) {
    int rec = ch >> 3, j = ch & 7;
    int ry = rec / 20, rx = rec - ry * 20;
    int yy = min(max(ty0 - 2 + ry, 0), HH - 1);
    int xx = min(max(tx0 - 2 + rx, 0), WW - 1);
    h8 v = *((const h8*)(xb + ((size_t)((yy << 7) + xx)) * 64) + (j ^ (rec & 7)));
    *(h8*)(smem + rec * 128 + j * 16) = v;
  }
  __syncthreads();

  f32x4 acc[4][2];     // [mt][nt]
  #pragma unroll
  for (int mt = 0; mt < 4; ++mt)
    #pragma unroll
    for (int nt = 0; nt < 2; ++nt) acc[mt][nt] = (f32x4){0.f, 0.f, 0.f, 0.f};

  const _Float16* wl = wtf2 + ln * 8;   // + (p*8 + mt*2 + kc)*512

  #pragma unroll
  for (int p = 0; p < PP; ++p) {
    h8 bfr[2][2];
    #pragma unroll
    for (int nt = 0; nt < 2; ++nt) {
      float sy = syr[p][nt], sx = sxr[p][nt];
      float y0f = floorf(sy), x0f = floorf(sx);
      float wy1 = sy - y0f, wy0 = 1.f - wy1;
      float wx1 = sx - x0f, wx0 = 1.f - wx1;
      int y0 = (int)y0f, x0i = (int)x0f;
      bool vy0 = (y0 >= 0) & (y0 < HH);
      bool vy1 = (y0 + 1 >= 0) & (y0 + 1 < HH);
      bool vx0 = (x0i >= 0) & (x0i < WW);
      bool vx1 = (x0i + 1 >= 0) & (x0i + 1 < WW);
      float w00 = (vy0 && vx0) ? wy0 * wx0 : 0.f;
      float w01 = (vy0 && vx1) ? wy0 * wx1 : 0.f;
      float w10 = (vy1 && vx0) ? wy1 * wx0 : 0.f;
      float w11 = (vy1 && vx1) ? wy1 * wx1 : 0.f;

      int iy0 = min(max(y0 - ty0 + 2, 0), 11);
      int iy1 = min(max(y0 + 1 - ty0 + 2, 0), 11);
      int ix0 = min(max(x0i - tx0 + 2, 0), 19);
      int ix1 = min(max(x0i + 1 - tx0 + 2, 0), 19);
      int r00 = iy0 * 20 + ix0, r01 = iy0 * 20 + ix1;
      int r10 = iy1 * 20 + ix0, r11 = iy1 * 20 + ix1;

      h8 v00a = *(const h8*)(smem + r00 * 128 + (((lk    ) ^ (r00 & 7)) << 4));
      h8 v00b = *(const h8*)(smem + r00 * 128 + (((lk + 4) ^ (r00 & 7)) << 4));
      h8 v01a = *(const h8*)(smem + r01 * 128 + (((lk    ) ^ (r01 & 7)) << 4));
      h8 v01b = *(const h8*)(smem + r01 * 128 + (((lk + 4) ^ (r01 & 7)) << 4));
      h8 v10a = *(const h8*)(smem + r10 * 128 + (((lk    ) ^ (r10 & 7)) << 4));
      h8 v10b = *(const h8*)(smem + r10 * 128 + (((lk + 4) ^ (r10 & 7)) << 4));
      h8 v11a = *(const h8*)(smem + r11 * 128 + (((lk    ) ^ (r11 & 7)) << 4));
      h8 v11b = *(const h8*)(smem + r11 * 128 + (((lk + 4) ^ (r11 & 7)) << 4));

      h8 w00v = (h8)(_Float16)w00;
      h8 w01v = (h8)(_Float16)w01;
      h8 w10v = (h8)(_Float16)w10;
      h8 w11v = (h8)(_Float16)w11;
      bfr[nt][0] = v00a * w00v + v01a * w01v + v10a * w10v + v11a * w11v;
      bfr[nt][1] = v00b * w00v + v01b * w01v + v10b * w10v + v11b * w11v;
    }

    #pragma unroll
    for (int mt = 0; mt < 4; ++mt) {
      h8 a0 = *(const h8*)(wl + (p * 8 + mt * 2) * 512);
      h8 a1 = *(const h8*)(wl + (p * 8 + mt * 2 + 1) * 512);
      #pragma unroll
      for (int nt = 0; nt < 2; ++nt) {
        acc[mt][nt] = __builtin_amdgcn_mfma_f32_16x16x32_f16(a0, bfr[nt][0], acc[mt][nt], 0, 0, 0);
        acc[mt][nt] = __builtin_amdgcn_mfma_f32_16x16x32_f16(a1, bfr[nt][1], acc[mt][nt], 0, 0, 0);
      }
    }
  }

  // ---- epilogue: C/D layout col=lane&15 (pixel), row=(lane>>4)*4+reg (m)
  #pragma unroll
  for (int nt = 0; nt < 2; ++nt) {
    int pix = ((y0r + nt) << 7) + tx0 + lm;
    #pragma unroll
    for (int mt = 0; mt < 4; ++mt) {
      #pragma unroll
      for (int r = 0; r < 4; ++r) {
        int m = mt * 16 + lk * 4 + r;
        out[((size_t)b * OO + m) * HWIMG + pix] = acc[mt][nt][r] + bias[m];
      }
    }
  }
}

// ---------------------------------------------------------------------------
extern "C" void kernel_launch(void* const* d_in, const int* in_sizes, int n_in,
                              void* d_out, int out_size, void* d_ws, size_t ws_size,
                              hipStream_t stream) {
  const float* x        = (const float*)d_in[0];
  const float* dw_w     = (const float*)d_in[1];
  const float* dw_b     = (const float*)d_in[2];
  const float* bn_gamma = (const float*)d_in[3];
  const float* bn_beta  = (const float*)d_in[4];
  const float* bn_mean  = (const float*)d_in[5];
  const float* bn_var   = (const float*)d_in[6];
  const float* pw_w     = (const float*)d_in[7];
  const float* pw_b     = (const float*)d_in[8];
  const float* weight   = (const float*)d_in[9];
  const float* bias     = (const float*)d_in[10];
  float* out = (float*)d_out;

  char* ws = (char*)d_ws;
  float* soff   = (float*)ws;                                  // 18*NTOT f32 = 9.44 MB
  size_t o1 = (size_t)2 * PP * NTOT * 4;
  _Float16* wtf2 = (_Float16*)(ws + o1);                       // 73728 B
  size_t o2 = o1 + (size_t)PP * OO * CC * 2;
  _Float16* xtb = (_Float16*)(ws + o2);                        // 16.8 MB
  size_t o3 = o2 + (size_t)NTOT * CC * 2;
  float* dwt = (float*)(ws + o3);                              // 2304 B
  float* bnA = (float*)(ws + o3 + 2304);
  float* bnB = (float*)(ws + o3 + 2304 + 256);

  k_prep<<<145, 256, 0, stream>>>(weight, dw_w, dw_b, bn_gamma, bn_beta,
                                  bn_mean, bn_var, wtf2, dwt, bnA, bnB);
  k_tr<<<NTOT / 64, 256, 0, stream>>>(x, xtb);
  k_off2<<<NTOT / 256, 512, 0, stream>>>(xtb, dwt, bnA, bnB, pw_w, pw_b, soff);
  k_main<<<NTOT / 128, 256, 0, stream>>>(xtb, soff, wtf2, bias, out);
}

// Round 15
// 76.457 us; speedup vs baseline: 4.7509x; 1.0084x over previous
//
#include <hip/hip_runtime.h>
#include <math.h>

#define BB 8
#define CC 64
#define OO 64
#define HH 128
#define WW 128
#define PP 9
#define HWIMG 16384           // H*W per batch
#define NTOT  131072          // B*H*W

typedef __attribute__((ext_vector_type(8))) _Float16 h8;
typedef __attribute__((ext_vector_type(2))) _Float16 h2;
typedef __attribute__((ext_vector_type(4))) float f32x4;

// ---------------------------------------------------------------------------
// Kernel 0: prep. blocks 0..143: wtf2 coalesced MFMA-A layout (r14):
//   i: e=i&7, ln=(i>>3)&63, kc=(i>>9)&1, mt=(i>>10)&3, p=i>>12
//   value = w[o=mt*16+(ln&15)][c=kc*32+(ln>>4)*8+e][p]
// block 144: dwt[tap][c], bnA[c], bnB[c].
// ---------------------------------------------------------------------------
__global__ void k_prep(const float* __restrict__ w,
                       const float* __restrict__ dw_w,
                       const float* __restrict__ dw_b,
                       const float* __restrict__ gamma,
                       const float* __restrict__ beta,
                       const float* __restrict__ mean,
                       const float* __restrict__ var,
                       _Float16* __restrict__ wtf2,
                       float* __restrict__ dwt,
                       float* __restrict__ bnA,
                       float* __restrict__ bnB) {
  int bid = blockIdx.x, t = threadIdx.x;
  if (bid < 144) {
    int i = bid * 256 + t;
    int e  = i & 7;
    int ln = (i >> 3) & 63;
    int kc = (i >> 9) & 1;
    int mt = (i >> 10) & 3;
    int p  = i >> 12;
    int o = mt * 16 + (ln & 15);
    int c = kc * 32 + (ln >> 4) * 8 + e;
    wtf2[i] = (_Float16)w[(o * 64 + c) * 9 + p];
  } else {
    if (t < 64) {
      float A = gamma[t] * rsqrtf(var[t] + 1e-5f);
      bnA[t] = A;
      bnB[t] = (dw_b[t] - mean[t]) * A + beta[t];
    }
    for (int i = t; i < 576; i += 256) {
      int tap = i % 9, c = i / 9;
      dwt[tap * 64 + c] = dw_w[c * 9 + tap];
    }
  }
}

// ---------------------------------------------------------------------------
// Staging helper for k_stage: reads x (f32 NCHW) rows in an aligned 24-float
// window (window start ws = tx0-1-SHIFT), converts to f16, writes the 18x18
// halo records (zero-padded outside the image) into swizzled LDS.
// SHIFT = 3 interior, -1 left-edge (tx0==0), 7 right-edge (tx0==112).
// All array indices compile-time (rule #20).
// ---------------------------------------------------------------------------
template<int SHIFT>
__device__ __forceinline__ void stage_tile(const float* __restrict__ xb0,
                                           char* __restrict__ lsm,
                                           int ty0, int tx0, int tid) {
  const int ws = tx0 - 1 - SHIFT;       // aligned (mod 4), in [0, 104]
  for (int it = tid; it < 576; it += 512) {
    int cp = it / 18;                   // channel pair 0..31
    int ry = it - cp * 18;              // halo row 0..17
    int y  = ty0 - 1 + ry;
    bool yv = (y >= 0) && (y < HH);
    int chunk = cp >> 2;
    int bofs  = (cp & 3) * 4;
    float a0[24], a1[24];
    if (yv) {
      const float* p0 = xb0 + (((size_t)(2 * cp)) << 14) + (y << 7) + ws;
      const float* p1 = p0 + HWIMG;
      #pragma unroll
      for (int q = 0; q < 6; ++q) {
        f32x4 t0 = *(const f32x4*)(p0 + q * 4);
        f32x4 t1 = *(const f32x4*)(p1 + q * 4);
        #pragma unroll
        for (int e = 0; e < 4; ++e) {
          a0[q * 4 + e] = t0[e];
          a1[q * 4 + e] = t1[e];
        }
      }
    }
    #pragma unroll
    for (int rx = 0; rx < 18; ++rx) {
      constexpr bool edge0 = (SHIFT == -1);
      constexpr bool edge7 = (SHIFT == 7);
      bool cv = !((edge0 && rx == 0) || (edge7 && rx == 17));
      constexpr int dummy = 0;
      int idx = rx + SHIFT;
      int idxc = (rx + SHIFT < 0) ? dummy : (rx + SHIFT >= 24 ? 23 : rx + SHIFT);
      (void)idx;
      float v0 = 0.f, v1 = 0.f;
      if (yv && cv) { v0 = a0[idxc]; v1 = a1[idxc]; }
      int rec = ry * 18 + rx;
      h2 hv;
      hv[0] = (_Float16)v0;
      hv[1] = (_Float16)v1;
      *(h2*)(lsm + rec * 128 + ((chunk ^ (rec & 7)) << 4) + bofs) = hv;
    }
  }
}

// ---------------------------------------------------------------------------
// Kernel 1: FUSED transpose + offsets. 16x16 px tile, 512 threads.
//  Phase A: stage 18x18 halo straight from x (f32 NCHW) -> swizzled LDS f16.
//  Phase B: write interior 16x16 records to xt (coalesced h8).
//  Phase C: offsets (r12-verified channel-split body) -> soff.
// ---------------------------------------------------------------------------
__global__ void __launch_bounds__(512, 4)
k_stage(const float* __restrict__ x,
        const float* __restrict__ dwt,
        const float* __restrict__ bnA,
        const float* __restrict__ bnB,
        const float* __restrict__ pw_w,
        const float* __restrict__ pw_b,
        _Float16* __restrict__ xt,
        float* __restrict__ soff) {
  __shared__ __attribute__((aligned(16))) char lsm[324 * 128];
  int bid = blockIdx.x;
  int b = bid & 7, t = bid >> 3;           // XCD k <- batch k; 64 tiles/img
  int ty0 = (t >> 3) * 16, tx0 = (t & 7) * 16;
  int tid = threadIdx.x;
  const float* xb0 = x + (((size_t)(b * CC)) << 14);

  int txi = t & 7;
  if (txi == 0)      stage_tile<-1>(xb0, lsm, ty0, tx0, tid);
  else if (txi == 7) stage_tile<7>(xb0, lsm, ty0, tx0, tid);
  else               stage_tile<3>(xb0, lsm, ty0, tx0, tid);
  __syncthreads();

  // ---- Phase B: interior 16x16 records -> xt (global chunk j from slot j^rec&7)
  for (int it = tid; it < 2048; it += 512) {
    int px = it >> 3, j = it & 7;
    int py = px >> 4, pxx = px & 15;
    int rec = (py + 1) * 18 + (pxx + 1);
    h8 v = *(const h8*)(lsm + rec * 128 + ((j ^ (rec & 7)) << 4));
    *((h8*)(xt + (((size_t)((b << 14) + ((ty0 + py) << 7) + tx0 + pxx)) * 64)) + j) = v;
  }

  // ---- Phase C: offsets (r12 body, verbatim math)
  int wv = tid >> 6, ln = tid & 63;
  int px = wv * 32 + (ln & 31);        // 8 waves x 32 px = 256 px
  int chalf = ln >> 5;                 // 0: ch 0..31, 1: ch 32..63
  int qy = px >> 4, qx = px & 15;

  float s[32];
  #pragma unroll
  for (int c = 0; c < 32; ++c) s[c] = 0.f;

  #pragma unroll
  for (int tap = 0; tap < 9; ++tap) {
    int dy = tap / 3 - 1, dx = tap % 3 - 1;
    int rec = (qy + dy + 1) * 18 + (qx + dx + 1);
    const f32x4* dwp4 = (const f32x4*)(dwt + tap * 64 + chalf * 32);
    #pragma unroll
    for (int gq = 0; gq < 4; ++gq) {
      int g = chalf * 4 + gq;
      h8 v = *(const h8*)(lsm + rec * 128 + ((g ^ (rec & 7)) << 4));
      f32x4 d0 = dwp4[gq * 2];
      f32x4 d1 = dwp4[gq * 2 + 1];
      #pragma unroll
      for (int e = 0; e < 4; ++e) s[gq * 8 + e]     += d0[e] * (float)v[e];
      #pragma unroll
      for (int e = 0; e < 4; ++e) s[gq * 8 + 4 + e] += d1[e] * (float)v[4 + e];
    }
  }

  {
    const f32x4* bnA4 = (const f32x4*)(bnA + chalf * 32);
    const f32x4* bnB4 = (const f32x4*)(bnB + chalf * 32);
    #pragma unroll
    for (int q = 0; q < 8; ++q) {
      f32x4 a4 = bnA4[q];
      f32x4 b4 = bnB4[q];
      #pragma unroll
      for (int e = 0; e < 4; ++e) {
        float v = s[q * 4 + e] * a4[e] + b4[e];
        s[q * 4 + e] = v / (1.f + __expf(-v));
      }
    }
  }

  float off[2 * PP];
  #pragma unroll
  for (int k = 0; k < 2 * PP; ++k) {
    const f32x4* pwp4 = (const f32x4*)(pw_w + k * CC + chalf * 32);
    float a = 0.f;
    #pragma unroll
    for (int j = 0; j < 8; ++j) {
      f32x4 pv = pwp4[j];
      a += pv[0] * s[4 * j];
      a += pv[1] * s[4 * j + 1];
      a += pv[2] * s[4 * j + 2];
      a += pv[3] * s[4 * j + 3];
    }
    off[k] = a + __shfl_xor(a, 32) + pw_b[k];
  }

  if (chalf == 0) {
    int y = ty0 + qy, xw = tx0 + qx;
    size_t idx = (size_t)(b << 14) + (y << 7) + xw;
    float fy = (float)y, fx = (float)xw;
    #pragma unroll
    for (int p = 0; p < PP; ++p) {
      soff[(size_t)(2 * p) * NTOT + idx]     = fy + off[2 * p]     + (float)(p / 3 - 1);
      soff[(size_t)(2 * p + 1) * NTOT + idx] = fx + off[2 * p + 1] + (float)(p % 3 - 1);
    }
  }
}

// ---------------------------------------------------------------------------
// Kernel 2: gather+MFMA (r14 champion, byte-identical).
// ---------------------------------------------------------------------------
__global__ void __launch_bounds__(256, 4)
k_main(const _Float16* __restrict__ xt,
       const float* __restrict__ soff,
       const _Float16* __restrict__ wtf2,
       const float* __restrict__ bias,
       float* __restrict__ out) {
  __shared__ __attribute__((aligned(16))) char smem[240 * 128];
  int bid = blockIdx.x;
  int b = bid & 7, t = bid >> 3;            // XCD k <- batch k; 128 tiles/img
  int ty0 = (t >> 3) * 8, tx0 = (t & 7) * 16;
  int tid = threadIdx.x, wid = tid >> 6, ln = tid & 63;
  int lm = ln & 15, lk = ln >> 4;
  const _Float16* xb = xt + (((size_t)b) << 14) * 64;

  // ---- preload ALL soff for this thread's 2 pixels (issued before staging)
  int y0r = ty0 + wid * 2;
  int ng0 = (b << 14) + (y0r << 7) + tx0 + lm;
  float syr[PP][2], sxr[PP][2];
  #pragma unroll
  for (int p = 0; p < PP; ++p) {
    syr[p][0] = soff[(size_t)(2 * p) * NTOT + ng0];
    syr[p][1] = soff[(size_t)(2 * p) * NTOT + ng0 + 128];
    sxr[p][0] = soff[(size_t)(2 * p + 1) * NTOT + ng0];
    sxr[p][1] = soff[(size_t)(2 * p + 1) * NTOT + ng0 + 128];
  }

  // ---- stage 12x20 halo records (row/col-clamped), chunk-swizzled
  for (int ch = tid; ch < 1920; ch += 256) {
    int rec = ch >> 3, j = ch & 7;
    int ry = rec / 20, rx = rec - ry * 20;
    int yy = min(max(ty0 - 2 + ry, 0), HH - 1);
    int xx = min(max(tx0 - 2 + rx, 0), WW - 1);
    h8 v = *((const h8*)(xb + ((size_t)((yy << 7) + xx)) * 64) + (j ^ (rec & 7)));
    *(h8*)(smem + rec * 128 + j * 16) = v;
  }
  __syncthreads();

  f32x4 acc[4][2];     // [mt][nt]
  #pragma unroll
  for (int mt = 0; mt < 4; ++mt)
    #pragma unroll
    for (int nt = 0; nt < 2; ++nt) acc[mt][nt] = (f32x4){0.f, 0.f, 0.f, 0.f};

  const _Float16* wl = wtf2 + ln * 8;   // + (p*8 + mt*2 + kc)*512

  #pragma unroll
  for (int p = 0; p < PP; ++p) {
    h8 bfr[2][2];
    #pragma unroll
    for (int nt = 0; nt < 2; ++nt) {
      float sy = syr[p][nt], sx = sxr[p][nt];
      float y0f = floorf(sy), x0f = floorf(sx);
      float wy1 = sy - y0f, wy0 = 1.f - wy1;
      float wx1 = sx - x0f, wx0 = 1.f - wx1;
      int y0 = (int)y0f, x0i = (int)x0f;
      bool vy0 = (y0 >= 0) & (y0 < HH);
      bool vy1 = (y0 + 1 >= 0) & (y0 + 1 < HH);
      bool vx0 = (x0i >= 0) & (x0i < WW);
      bool vx1 = (x0i + 1 >= 0) & (x0i + 1 < WW);
      float w00 = (vy0 && vx0) ? wy0 * wx0 : 0.f;
      float w01 = (vy0 && vx1) ? wy0 * wx1 : 0.f;
      float w10 = (vy1 && vx0) ? wy1 * wx0 : 0.f;
      float w11 = (vy1 && vx1) ? wy1 * wx1 : 0.f;

      int iy0 = min(max(y0 - ty0 + 2, 0), 11);
      int iy1 = min(max(y0 + 1 - ty0 + 2, 0), 11);
      int ix0 = min(max(x0i - tx0 + 2, 0), 19);
      int ix1 = min(max(x0i + 1 - tx0 + 2, 0), 19);
      int r00 = iy0 * 20 + ix0, r01 = iy0 * 20 + ix1;
      int r10 = iy1 * 20 + ix0, r11 = iy1 * 20 + ix1;

      h8 v00a = *(const h8*)(smem + r00 * 128 + (((lk    ) ^ (r00 & 7)) << 4));
      h8 v00b = *(const h8*)(smem + r00 * 128 + (((lk + 4) ^ (r00 & 7)) << 4));
      h8 v01a = *(const h8*)(smem + r01 * 128 + (((lk    ) ^ (r01 & 7)) << 4));
      h8 v01b = *(const h8*)(smem + r01 * 128 + (((lk + 4) ^ (r01 & 7)) << 4));
      h8 v10a = *(const h8*)(smem + r10 * 128 + (((lk    ) ^ (r10 & 7)) << 4));
      h8 v10b = *(const h8*)(smem + r10 * 128 + (((lk + 4) ^ (r10 & 7)) << 4));
      h8 v11a = *(const h8*)(smem + r11 * 128 + (((lk    ) ^ (r11 & 7)) << 4));
      h8 v11b = *(const h8*)(smem + r11 * 128 + (((lk + 4) ^ (r11 & 7)) << 4));

      h8 w00v = (h8)(_Float16)w00;
      h8 w01v = (h8)(_Float16)w01;
      h8 w10v = (h8)(_Float16)w10;
      h8 w11v = (h8)(_Float16)w11;
      bfr[nt][0] = v00a * w00v + v01a * w01v + v10a * w10v + v11a * w11v;
      bfr[nt][1] = v00b * w00v + v01b * w01v + v10b * w10v + v11b * w11v;
    }

    #pragma unroll
    for (int mt = 0; mt < 4; ++mt) {
      h8 a0 = *(const h8*)(wl + (p * 8 + mt * 2) * 512);
      h8 a1 = *(const h8*)(wl + (p * 8 + mt * 2 + 1) * 512);
      #pragma unroll
      for (int nt = 0; nt < 2; ++nt) {
        acc[mt][nt] = __builtin_amdgcn_mfma_f32_16x16x32_f16(a0, bfr[nt][0], acc[mt][nt], 0, 0, 0);
        acc[mt][nt] = __builtin_amdgcn_mfma_f32_16x16x32_f16(a1, bfr[nt][1], acc[mt][nt], 0, 0, 0);
      }
    }
  }

  // ---- epilogue: C/D layout col=lane&15 (pixel), row=(lane>>4)*4+reg (m)
  #pragma unroll
  for (int nt = 0; nt < 2; ++nt) {
    int pix = ((y0r + nt) << 7) + tx0 + lm;
    #pragma unroll
    for (int mt = 0; mt < 4; ++mt) {
      #pragma unroll
      for (int r = 0; r < 4; ++r) {
        int m = mt * 16 + lk * 4 + r;
        out[((size_t)b * OO + m) * HWIMG + pix] = acc[mt][nt][r] + bias[m];
      }
    }
  }
}

// ---------------------------------------------------------------------------
extern "C" void kernel_launch(void* const* d_in, const int* in_sizes, int n_in,
                              void* d_out, int out_size, void* d_ws, size_t ws_size,
                              hipStream_t stream) {
  const float* x        = (const float*)d_in[0];
  const float* dw_w     = (const float*)d_in[1];
  const float* dw_b     = (const float*)d_in[2];
  const float* bn_gamma = (const float*)d_in[3];
  const float* bn_beta  = (const float*)d_in[4];
  const float* bn_mean  = (const float*)d_in[5];
  const float* bn_var   = (const float*)d_in[6];
  const float* pw_w     = (const float*)d_in[7];
  const float* pw_b     = (const float*)d_in[8];
  const float* weight   = (const float*)d_in[9];
  const float* bias     = (const float*)d_in[10];
  float* out = (float*)d_out;

  char* ws = (char*)d_ws;
  float* soff   = (float*)ws;                                  // 18*NTOT f32 = 9.44 MB
  size_t o1 = (size_t)2 * PP * NTOT * 4;
  _Float16* wtf2 = (_Float16*)(ws + o1);                       // 73728 B
  size_t o2 = o1 + (size_t)PP * OO * CC * 2;
  _Float16* xtb = (_Float16*)(ws + o2);                        // 16.8 MB
  size_t o3 = o2 + (size_t)NTOT * CC * 2;
  float* dwt = (float*)(ws + o3);                              // 2304 B
  float* bnA = (float*)(ws + o3 + 2304);
  float* bnB = (float*)(ws + o3 + 2304 + 256);

  k_prep<<<145, 256, 0, stream>>>(weight, dw_w, dw_b, bn_gamma, bn_beta,
                                  bn_mean, bn_var, wtf2, dwt, bnA, bnB);
  k_stage<<<NTOT / 256, 512, 0, stream>>>(x, dwt, bnA, bnB, pw_w, pw_b,
                                          xtb, soff);
  k_main<<<NTOT / 128, 256, 0, stream>>>(xtb, soff, wtf2, bias, out);
}

// Round 16
// 58.308 us; speedup vs baseline: 6.2296x; 1.3113x over previous
//
#include <hip/hip_runtime.h>
#include <math.h>

#define BB 8
#define CC 64
#define OO 64
#define HH 128
#define WW 128
#define PP 9
#define HWIMG 16384           // H*W per batch
#define NTOT  131072          // B*H*W

typedef __attribute__((ext_vector_type(8))) _Float16 h8;
typedef __attribute__((ext_vector_type(2))) _Float16 h2;
typedef __attribute__((ext_vector_type(4))) float f32x4;

// ---------------------------------------------------------------------------
// Kernel 0: prep.
//  blocks 0..143: wtf2 coalesced MFMA-A layout (r14, verified).
//  block 144: dwt[tap][c], bnA[c], bnB[c], pwb[32] (pw_b zero-padded),
//             pwa: offset-conv A-frags: pwa[(mt*2+kc)*512 + ln*8 + e] =
//                  pw_w[k_off=mt*16+(ln&15)][c=kc*32+((ln>>4)&3)*8+e], 0 if k_off>=18
// ---------------------------------------------------------------------------
__global__ void k_prep(const float* __restrict__ w,
                       const float* __restrict__ dw_w,
                       const float* __restrict__ dw_b,
                       const float* __restrict__ gamma,
                       const float* __restrict__ beta,
                       const float* __restrict__ mean,
                       const float* __restrict__ var,
                       const float* __restrict__ pw_w,
                       const float* __restrict__ pw_b,
                       _Float16* __restrict__ wtf2,
                       float* __restrict__ dwt,
                       float* __restrict__ bnA,
                       float* __restrict__ bnB,
                       _Float16* __restrict__ pwa,
                       float* __restrict__ pwb) {
  int bid = blockIdx.x, t = threadIdx.x;
  if (bid < 144) {
    int i = bid * 256 + t;
    int e  = i & 7;
    int ln = (i >> 3) & 63;
    int kc = (i >> 9) & 1;
    int mt = (i >> 10) & 3;
    int p  = i >> 12;
    int o = mt * 16 + (ln & 15);
    int c = kc * 32 + (ln >> 4) * 8 + e;
    wtf2[i] = (_Float16)w[(o * 64 + c) * 9 + p];
  } else {
    if (t < 64) {
      float A = gamma[t] * rsqrtf(var[t] + 1e-5f);
      bnA[t] = A;
      bnB[t] = (dw_b[t] - mean[t]) * A + beta[t];
    }
    if (t < 32) pwb[t] = (t < 18) ? pw_b[t] : 0.f;
    for (int i = t; i < 576; i += 256) {
      int tap = i % 9, c = i / 9;
      dwt[tap * 64 + c] = dw_w[c * 9 + tap];
    }
    for (int i = t; i < 2048; i += 256) {
      int e  = i & 7;
      int ln = (i >> 3) & 63;
      int kc = (i >> 9) & 1;
      int mt = (i >> 10) & 1;
      int ko = mt * 16 + (ln & 15);
      int c  = kc * 32 + ((ln >> 4) & 3) * 8 + e;
      pwa[i] = (ko < 18) ? (_Float16)pw_w[ko * 64 + c] : (_Float16)0.f;
    }
  }
}

// ---------------------------------------------------------------------------
// Kernel 1: x NCHW f32 -> xt[b][pix][c] f16 (NHWC) (r14 verbatim, known good)
// ---------------------------------------------------------------------------
__global__ void __launch_bounds__(256, 4)
k_tr(const float* __restrict__ x, _Float16* __restrict__ xt) {
  __shared__ _Float16 lt[64][66];
  int bid = blockIdx.x;
  int vbid = (bid & 7) * 256 + (bid >> 3);    // XCD k <- batch k
  int tid = threadIdx.x;
  int wid = tid >> 6, ln = tid & 63;
  int b = vbid >> 8;
  int pix0 = (vbid & 255) * 64;
  const float* xbb = x + (size_t)b * CC * HWIMG;

  #pragma unroll
  for (int i = 0; i < 8; ++i) {
    int c0 = (wid * 8 + i) * 2;
    float v0 = xbb[(size_t)c0 * HWIMG + pix0 + ln];
    float v1 = xbb[(size_t)(c0 + 1) * HWIMG + pix0 + ln];
    h2 hv;
    hv[0] = (_Float16)v0;
    hv[1] = (_Float16)v1;
    *(h2*)&lt[ln][c0] = hv;
  }
  __syncthreads();

  int pq = tid >> 2, q = tid & 3;
  h8 o0, o1;
  #pragma unroll
  for (int j = 0; j < 4; ++j) {
    h2 v = *(h2*)&lt[pq][q * 16 + 2 * j];
    o0[2 * j] = v[0];
    o0[2 * j + 1] = v[1];
  }
  #pragma unroll
  for (int j = 0; j < 4; ++j) {
    h2 v = *(h2*)&lt[pq][q * 16 + 8 + 2 * j];
    o1[2 * j] = v[0];
    o1[2 * j + 1] = v[1];
  }
  _Float16* op = xt + ((size_t)((b << 14) + pix0 + pq)) * 64 + q * 16;
  *(h8*)op = o0;
  *(h8*)(op + 8) = o1;
}

// ---------------------------------------------------------------------------
// Kernel 2: FUSED offsets (MFMA) + gather + MFMA. 8x16 px tile, 12x20 halo.
// Phase 1: lane (lm,lk) computes dwconv+BN+SiLU for pixel lm (2 rows) over
//   its 16 channels from the staged halo (per-tap zero for conv padding),
//   packs f16 B-frags, 8 MFMAs vs pwa (C-in = pwb) -> aco = 18 offsets in
//   C/D layout. Phase 2: champion gather+MFMA; (sy,sx) via 2 shfl per (p,nt).
// ---------------------------------------------------------------------------
__global__ void __launch_bounds__(256, 4)
k_main(const _Float16* __restrict__ xt,
       const float* __restrict__ dwt,
       const float* __restrict__ bnA,
       const float* __restrict__ bnB,
       const _Float16* __restrict__ pwa,
       const float* __restrict__ pwb,
       const _Float16* __restrict__ wtf2,
       const float* __restrict__ bias,
       float* __restrict__ out) {
  __shared__ __attribute__((aligned(16))) char smem[240 * 128];
  int bid = blockIdx.x;
  int b = bid & 7, t = bid >> 3;            // XCD k <- batch k; 128 tiles/img
  int ty0 = (t >> 3) * 8, tx0 = (t & 7) * 16;
  int tid = threadIdx.x, wid = tid >> 6, ln = tid & 63;
  int lm = ln & 15, lk = ln >> 4;
  const _Float16* xb = xt + (((size_t)b) << 14) * 64;

  // ---- stage 12x20 halo records (row/col-clamped), chunk-swizzled
  for (int ch = tid; ch < 1920; ch += 256) {
    int rec = ch >> 3, j = ch & 7;
    int ry = rec / 20, rx = rec - ry * 20;
    int yy = min(max(ty0 - 2 + ry, 0), HH - 1);
    int xx = min(max(tx0 - 2 + rx, 0), WW - 1);
    h8 v = *((const h8*)(xb + ((size_t)((yy << 7) + xx)) * 64) + (j ^ (rec & 7)));
    *(h8*)(smem + rec * 128 + j * 16) = v;
  }
  __syncthreads();

  int qy0 = wid * 2;             // wave's 2 pixel rows in tile
  int y0r = ty0 + qy0;

  // ======== Phase 1: offsets via MFMA ========
  float s[2][16];
  #pragma unroll
  for (int nt = 0; nt < 2; ++nt)
    #pragma unroll
    for (int e = 0; e < 16; ++e) s[nt][e] = 0.f;

  #pragma unroll
  for (int tap = 0; tap < 9; ++tap) {
    int dy = tap / 3 - 1, dx = tap % 3 - 1;
    int xc2 = tx0 + lm + dx;
    bool cok = (xc2 >= 0) & (xc2 < WW);
    const float* dwp = dwt + tap * 64;
    f32x4 d0a = *(const f32x4*)(dwp + lk * 8);
    f32x4 d0b = *(const f32x4*)(dwp + lk * 8 + 4);
    f32x4 d1a = *(const f32x4*)(dwp + 32 + lk * 8);
    f32x4 d1b = *(const f32x4*)(dwp + 32 + lk * 8 + 4);
    #pragma unroll
    for (int nt = 0; nt < 2; ++nt) {
      int ry = y0r + nt + dy;
      bool ok = cok & (ry >= 0) & (ry < HH);
      int rec = (qy0 + nt + dy + 2) * 20 + (lm + dx + 2);
      h8 v0 = *(const h8*)(smem + rec * 128 + (((lk    ) ^ (rec & 7)) << 4));
      h8 v1 = *(const h8*)(smem + rec * 128 + (((lk + 4) ^ (rec & 7)) << 4));
      if (!ok) { v0 = (h8)(_Float16)0.f; v1 = (h8)(_Float16)0.f; }
      #pragma unroll
      for (int e = 0; e < 4; ++e) {
        s[nt][e]      += d0a[e] * (float)v0[e];
        s[nt][4 + e]  += d0b[e] * (float)v0[4 + e];
        s[nt][8 + e]  += d1a[e] * (float)v1[e];
        s[nt][12 + e] += d1b[e] * (float)v1[4 + e];
      }
    }
  }

  // BN + SiLU + pack to f16 B-frags
  h8 bo[2][2];   // [nt][kc]
  {
    f32x4 ba0 = *(const f32x4*)(bnA + lk * 8);
    f32x4 ba1 = *(const f32x4*)(bnA + lk * 8 + 4);
    f32x4 ba2 = *(const f32x4*)(bnA + 32 + lk * 8);
    f32x4 ba3 = *(const f32x4*)(bnA + 32 + lk * 8 + 4);
    f32x4 bb0 = *(const f32x4*)(bnB + lk * 8);
    f32x4 bb1 = *(const f32x4*)(bnB + lk * 8 + 4);
    f32x4 bb2 = *(const f32x4*)(bnB + 32 + lk * 8);
    f32x4 bb3 = *(const f32x4*)(bnB + 32 + lk * 8 + 4);
    #pragma unroll
    for (int nt = 0; nt < 2; ++nt) {
      #pragma unroll
      for (int e = 0; e < 4; ++e) {
        float v;
        v = s[nt][e]      * ba0[e] + bb0[e]; s[nt][e]      = v / (1.f + __expf(-v));
        v = s[nt][4 + e]  * ba1[e] + bb1[e]; s[nt][4 + e]  = v / (1.f + __expf(-v));
        v = s[nt][8 + e]  * ba2[e] + bb2[e]; s[nt][8 + e]  = v / (1.f + __expf(-v));
        v = s[nt][12 + e] * ba3[e] + bb3[e]; s[nt][12 + e] = v / (1.f + __expf(-v));
      }
      #pragma unroll
      for (int e = 0; e < 8; ++e) {
        bo[nt][0][e] = (_Float16)s[nt][e];
        bo[nt][1][e] = (_Float16)s[nt][8 + e];
      }
    }
  }

  // offset MFMA: aco[mt][nt], C-in = padded bias
  f32x4 aco[2][2];
  {
    f32x4 c0 = *(const f32x4*)(pwb + lk * 4);
    f32x4 c1 = *(const f32x4*)(pwb + 16 + lk * 4);
    aco[0][0] = c0; aco[0][1] = c0;
    aco[1][0] = c1; aco[1][1] = c1;
  }
  #pragma unroll
  for (int kc = 0; kc < 2; ++kc) {
    #pragma unroll
    for (int mt = 0; mt < 2; ++mt) {
      h8 A = *(const h8*)(pwa + (mt * 2 + kc) * 512 + ln * 8);
      #pragma unroll
      for (int nt = 0; nt < 2; ++nt)
        aco[mt][nt] = __builtin_amdgcn_mfma_f32_16x16x32_f16(A, bo[nt][kc], aco[mt][nt], 0, 0, 0);
    }
  }

  // ======== Phase 2: gather + MFMA (champion body) ========
  f32x4 acc[4][2];     // [mt][nt]
  #pragma unroll
  for (int mt = 0; mt < 4; ++mt)
    #pragma unroll
    for (int nt = 0; nt < 2; ++nt) acc[mt][nt] = (f32x4){0.f, 0.f, 0.f, 0.f};

  const _Float16* wl = wtf2 + ln * 8;   // + (p*8 + mt*2 + kc)*512

  #pragma unroll
  for (int p = 0; p < PP; ++p) {
    h8 bfr[2][2];
    #pragma unroll
    for (int nt = 0; nt < 2; ++nt) {
      // offsets of pixel (row y0r+nt, col tx0+lm) live in lanes (*, lm):
      // k_off=m at lane ((m&15)>>2)*16+lm, acc[mt=m>>4][nt], element m&3.
      const int ky = 2 * p, kx = 2 * p + 1;
      float offy = __shfl(aco[ky >> 4][nt][ky & 3], ((ky & 15) >> 2) * 16 + lm);
      float offx = __shfl(aco[kx >> 4][nt][kx & 3], ((kx & 15) >> 2) * 16 + lm);
      float sy = offy + (float)(y0r + nt) + (float)(p / 3 - 1);
      float sx = offx + (float)(tx0 + lm) + (float)(p % 3 - 1);

      float y0f = floorf(sy), x0f = floorf(sx);
      float wy1 = sy - y0f, wy0 = 1.f - wy1;
      float wx1 = sx - x0f, wx0 = 1.f - wx1;
      int y0 = (int)y0f, x0i = (int)x0f;
      bool vy0 = (y0 >= 0) & (y0 < HH);
      bool vy1 = (y0 + 1 >= 0) & (y0 + 1 < HH);
      bool vx0 = (x0i >= 0) & (x0i < WW);
      bool vx1 = (x0i + 1 >= 0) & (x0i + 1 < WW);
      float w00 = (vy0 && vx0) ? wy0 * wx0 : 0.f;
      float w01 = (vy0 && vx1) ? wy0 * wx1 : 0.f;
      float w10 = (vy1 && vx0) ? wy1 * wx0 : 0.f;
      float w11 = (vy1 && vx1) ? wy1 * wx1 : 0.f;

      int iy0 = min(max(y0 - ty0 + 2, 0), 11);
      int iy1 = min(max(y0 + 1 - ty0 + 2, 0), 11);
      int ix0 = min(max(x0i - tx0 + 2, 0), 19);
      int ix1 = min(max(x0i + 1 - tx0 + 2, 0), 19);
      int r00 = iy0 * 20 + ix0, r01 = iy0 * 20 + ix1;
      int r10 = iy1 * 20 + ix0, r11 = iy1 * 20 + ix1;

      h8 v00a = *(const h8*)(smem + r00 * 128 + (((lk    ) ^ (r00 & 7)) << 4));
      h8 v00b = *(const h8*)(smem + r00 * 128 + (((lk + 4) ^ (r00 & 7)) << 4));
      h8 v01a = *(const h8*)(smem + r01 * 128 + (((lk    ) ^ (r01 & 7)) << 4));
      h8 v01b = *(const h8*)(smem + r01 * 128 + (((lk + 4) ^ (r01 & 7)) << 4));
      h8 v10a = *(const h8*)(smem + r10 * 128 + (((lk    ) ^ (r10 & 7)) << 4));
      h8 v10b = *(const h8*)(smem + r10 * 128 + (((lk + 4) ^ (r10 & 7)) << 4));
      h8 v11a = *(const h8*)(smem + r11 * 128 + (((lk    ) ^ (r11 & 7)) << 4));
      h8 v11b = *(const h8*)(smem + r11 * 128 + (((lk + 4) ^ (r11 & 7)) << 4));

      h8 w00v = (h8)(_Float16)w00;
      h8 w01v = (h8)(_Float16)w01;
      h8 w10v = (h8)(_Float16)w10;
      h8 w11v = (h8)(_Float16)w11;
      bfr[nt][0] = v00a * w00v + v01a * w01v + v10a * w10v + v11a * w11v;
      bfr[nt][1] = v00b * w00v + v01b * w01v + v10b * w10v + v11b * w11v;
    }

    #pragma unroll
    for (int mt = 0; mt < 4; ++mt) {
      h8 a0 = *(const h8*)(wl + (p * 8 + mt * 2) * 512);
      h8 a1 = *(const h8*)(wl + (p * 8 + mt * 2 + 1) * 512);
      #pragma unroll
      for (int nt = 0; nt < 2; ++nt) {
        acc[mt][nt] = __builtin_amdgcn_mfma_f32_16x16x32_f16(a0, bfr[nt][0], acc[mt][nt], 0, 0, 0);
        acc[mt][nt] = __builtin_amdgcn_mfma_f32_16x16x32_f16(a1, bfr[nt][1], acc[mt][nt], 0, 0, 0);
      }
    }
  }

  // ---- epilogue: C/D layout col=lane&15 (pixel), row=(lane>>4)*4+reg (m)
  #pragma unroll
  for (int nt = 0; nt < 2; ++nt) {
    int pix = ((y0r + nt) << 7) + tx0 + lm;
    #pragma unroll
    for (int mt = 0; mt < 4; ++mt) {
      #pragma unroll
      for (int r = 0; r < 4; ++r) {
        int m = mt * 16 + lk * 4 + r;
        out[((size_t)b * OO + m) * HWIMG + pix] = acc[mt][nt][r] + bias[m];
      }
    }
  }
}

// ---------------------------------------------------------------------------
extern "C" void kernel_launch(void* const* d_in, const int* in_sizes, int n_in,
                              void* d_out, int out_size, void* d_ws, size_t ws_size,
                              hipStream_t stream) {
  const float* x        = (const float*)d_in[0];
  const float* dw_w     = (const float*)d_in[1];
  const float* dw_b     = (const float*)d_in[2];
  const float* bn_gamma = (const float*)d_in[3];
  const float* bn_beta  = (const float*)d_in[4];
  const float* bn_mean  = (const float*)d_in[5];
  const float* bn_var   = (const float*)d_in[6];
  const float* pw_w     = (const float*)d_in[7];
  const float* pw_b     = (const float*)d_in[8];
  const float* weight   = (const float*)d_in[9];
  const float* bias     = (const float*)d_in[10];
  float* out = (float*)d_out;

  char* ws = (char*)d_ws;
  _Float16* wtf2 = (_Float16*)ws;                              // 73728 B
  size_t o1 = (size_t)PP * OO * CC * 2;
  _Float16* xtb = (_Float16*)(ws + o1);                        // 16.8 MB
  size_t o2 = o1 + (size_t)NTOT * CC * 2;
  float* dwt = (float*)(ws + o2);                              // 2304 B
  float* bnA = (float*)(ws + o2 + 2304);                       // 256 B
  float* bnB = (float*)(ws + o2 + 2304 + 256);                 // 256 B
  _Float16* pwa = (_Float16*)(ws + o2 + 2304 + 512);           // 4096 B
  float* pwb = (float*)(ws + o2 + 2304 + 512 + 4096);          // 128 B

  k_prep<<<145, 256, 0, stream>>>(weight, dw_w, dw_b, bn_gamma, bn_beta,
                                  bn_mean, bn_var, pw_w, pw_b,
                                  wtf2, dwt, bnA, bnB, pwa, pwb);
  k_tr<<<NTOT / 64, 256, 0, stream>>>(x, xtb);
  k_main<<<NTOT / 128, 256, 0, stream>>>(xtb, dwt, bnA, bnB, pwa, pwb,
                                         wtf2, bias, out);
}

// Round 17
// 54.111 us; speedup vs baseline: 6.7129x; 1.0776x over previous
//
#include <hip/hip_runtime.h>
#include <math.h>

#define BB 8
#define CC 64
#define OO 64
#define HH 128
#define WW 128
#define PP 9
#define HWIMG 16384           // H*W per batch
#define NTOT  131072          // B*H*W

typedef __attribute__((ext_vector_type(8))) _Float16 h8;
typedef __attribute__((ext_vector_type(2))) _Float16 h2;
typedef __attribute__((ext_vector_type(4))) float f32x4;
typedef __attribute__((ext_vector_type(4))) unsigned int u32x4;

// ---------------------------------------------------------------------------
// Kernel 0: prep (r16 verbatim).
// ---------------------------------------------------------------------------
__global__ void k_prep(const float* __restrict__ w,
                       const float* __restrict__ dw_w,
                       const float* __restrict__ dw_b,
                       const float* __restrict__ gamma,
                       const float* __restrict__ beta,
                       const float* __restrict__ mean,
                       const float* __restrict__ var,
                       const float* __restrict__ pw_w,
                       const float* __restrict__ pw_b,
                       _Float16* __restrict__ wtf2,
                       float* __restrict__ dwt,
                       float* __restrict__ bnA,
                       float* __restrict__ bnB,
                       _Float16* __restrict__ pwa,
                       float* __restrict__ pwb) {
  int bid = blockIdx.x, t = threadIdx.x;
  if (bid < 144) {
    int i = bid * 256 + t;
    int e  = i & 7;
    int ln = (i >> 3) & 63;
    int kc = (i >> 9) & 1;
    int mt = (i >> 10) & 3;
    int p  = i >> 12;
    int o = mt * 16 + (ln & 15);
    int c = kc * 32 + (ln >> 4) * 8 + e;
    wtf2[i] = (_Float16)w[(o * 64 + c) * 9 + p];
  } else {
    if (t < 64) {
      float A = gamma[t] * rsqrtf(var[t] + 1e-5f);
      bnA[t] = A;
      bnB[t] = (dw_b[t] - mean[t]) * A + beta[t];
    }
    if (t < 32) pwb[t] = (t < 18) ? pw_b[t] : 0.f;
    for (int i = t; i < 576; i += 256) {
      int tap = i % 9, c = i / 9;
      dwt[tap * 64 + c] = dw_w[c * 9 + tap];
    }
    for (int i = t; i < 2048; i += 256) {
      int e  = i & 7;
      int ln = (i >> 3) & 63;
      int kc = (i >> 9) & 1;
      int mt = (i >> 10) & 1;
      int ko = mt * 16 + (ln & 15);
      int c  = kc * 32 + ((ln >> 4) & 3) * 8 + e;
      pwa[i] = (ko < 18) ? (_Float16)pw_w[ko * 64 + c] : (_Float16)0.f;
    }
  }
}

// ---------------------------------------------------------------------------
// Kernel 1: x NCHW f32 -> xt[b][pix][c] f16 (NHWC) (verbatim, known good)
// ---------------------------------------------------------------------------
__global__ void __launch_bounds__(256, 4)
k_tr(const float* __restrict__ x, _Float16* __restrict__ xt) {
  __shared__ _Float16 lt[64][66];
  int bid = blockIdx.x;
  int vbid = (bid & 7) * 256 + (bid >> 3);    // XCD k <- batch k
  int tid = threadIdx.x;
  int wid = tid >> 6, ln = tid & 63;
  int b = vbid >> 8;
  int pix0 = (vbid & 255) * 64;
  const float* xbb = x + (size_t)b * CC * HWIMG;

  #pragma unroll
  for (int i = 0; i < 8; ++i) {
    int c0 = (wid * 8 + i) * 2;
    float v0 = xbb[(size_t)c0 * HWIMG + pix0 + ln];
    float v1 = xbb[(size_t)(c0 + 1) * HWIMG + pix0 + ln];
    h2 hv;
    hv[0] = (_Float16)v0;
    hv[1] = (_Float16)v1;
    *(h2*)&lt[ln][c0] = hv;
  }
  __syncthreads();

  int pq = tid >> 2, q = tid & 3;
  h8 o0, o1;
  #pragma unroll
  for (int j = 0; j < 4; ++j) {
    h2 v = *(h2*)&lt[pq][q * 16 + 2 * j];
    o0[2 * j] = v[0];
    o0[2 * j + 1] = v[1];
  }
  #pragma unroll
  for (int j = 0; j < 4; ++j) {
    h2 v = *(h2*)&lt[pq][q * 16 + 8 + 2 * j];
    o1[2 * j] = v[0];
    o1[2 * j + 1] = v[1];
  }
  _Float16* op = xt + ((size_t)((b << 14) + pix0 + pq)) * 64 + q * 16;
  *(h8*)op = o0;
  *(h8*)(op + 8) = o1;
}

// ---------------------------------------------------------------------------
// Fused tile body. BORDER=true keeps full validity/clamp math (r16 verbatim);
// BORDER=false (84/128 tiles) skips it — valid under the same |off|<0.9
// invariant the clamped-halo gather already relies on.
// Offsets leave phase 1 via a 6KB LDS side-buffer (packed f16), read back
// per-pixel into registers — no per-p shfl on the critical path.
// ---------------------------------------------------------------------------
template<bool BORDER>
__device__ __forceinline__ void tile_body(
    const _Float16* __restrict__ xb,
    const float* __restrict__ dwt,
    const float* __restrict__ bnA,
    const float* __restrict__ bnB,
    const _Float16* __restrict__ pwa,
    const float* __restrict__ pwb,
    const _Float16* __restrict__ wtf2,
    const float* __restrict__ bias,
    float* __restrict__ out,
    char* smem, int b, int ty0, int tx0, int tid) {
  char* off_lds = smem + 240 * 128;
  int wid = tid >> 6, ln = tid & 63;
  int lm = ln & 15, lk = ln >> 4;

  // ---- stage 12x20 halo records (row/col-clamped), chunk-swizzled
  for (int ch = tid; ch < 1920; ch += 256) {
    int rec = ch >> 3, j = ch & 7;
    int ry = rec / 20, rx = rec - ry * 20;
    int yy = min(max(ty0 - 2 + ry, 0), HH - 1);
    int xx = min(max(tx0 - 2 + rx, 0), WW - 1);
    h8 v = *((const h8*)(xb + ((size_t)((yy << 7) + xx)) * 64) + (j ^ (rec & 7)));
    *(h8*)(smem + rec * 128 + j * 16) = v;
  }
  __syncthreads();

  int qy0 = wid * 2;
  int y0r = ty0 + qy0;

  // ======== Phase 1: offsets via MFMA ========
  float s[2][16];
  #pragma unroll
  for (int nt = 0; nt < 2; ++nt)
    #pragma unroll
    for (int e = 0; e < 16; ++e) s[nt][e] = 0.f;

  #pragma unroll
  for (int tap = 0; tap < 9; ++tap) {
    int dy = tap / 3 - 1, dx = tap % 3 - 1;
    int xc2 = tx0 + lm + dx;
    bool cok = (xc2 >= 0) & (xc2 < WW);
    const float* dwp = dwt + tap * 64;
    f32x4 d0a = *(const f32x4*)(dwp + lk * 8);
    f32x4 d0b = *(const f32x4*)(dwp + lk * 8 + 4);
    f32x4 d1a = *(const f32x4*)(dwp + 32 + lk * 8);
    f32x4 d1b = *(const f32x4*)(dwp + 32 + lk * 8 + 4);
    #pragma unroll
    for (int nt = 0; nt < 2; ++nt) {
      int rec = (qy0 + nt + dy + 2) * 20 + (lm + dx + 2);
      h8 v0 = *(const h8*)(smem + rec * 128 + (((lk    ) ^ (rec & 7)) << 4));
      h8 v1 = *(const h8*)(smem + rec * 128 + (((lk + 4) ^ (rec & 7)) << 4));
      if (BORDER) {
        int ry = y0r + nt + dy;
        bool ok = cok & (ry >= 0) & (ry < HH);
        if (!ok) { v0 = (h8)(_Float16)0.f; v1 = (h8)(_Float16)0.f; }
      }
      #pragma unroll
      for (int e = 0; e < 4; ++e) {
        s[nt][e]      += d0a[e] * (float)v0[e];
        s[nt][4 + e]  += d0b[e] * (float)v0[4 + e];
        s[nt][8 + e]  += d1a[e] * (float)v1[e];
        s[nt][12 + e] += d1b[e] * (float)v1[4 + e];
      }
    }
  }

  // BN + SiLU (rcp form) + pack to f16 B-frags
  h8 bo[2][2];   // [nt][kc]
  {
    f32x4 ba0 = *(const f32x4*)(bnA + lk * 8);
    f32x4 ba1 = *(const f32x4*)(bnA + lk * 8 + 4);
    f32x4 ba2 = *(const f32x4*)(bnA + 32 + lk * 8);
    f32x4 ba3 = *(const f32x4*)(bnA + 32 + lk * 8 + 4);
    f32x4 bb0 = *(const f32x4*)(bnB + lk * 8);
    f32x4 bb1 = *(const f32x4*)(bnB + lk * 8 + 4);
    f32x4 bb2 = *(const f32x4*)(bnB + 32 + lk * 8);
    f32x4 bb3 = *(const f32x4*)(bnB + 32 + lk * 8 + 4);
    #pragma unroll
    for (int nt = 0; nt < 2; ++nt) {
      #pragma unroll
      for (int e = 0; e < 4; ++e) {
        float v;
        v = s[nt][e]      * ba0[e] + bb0[e];
        s[nt][e]      = v * __builtin_amdgcn_rcpf(1.f + __expf(-v));
        v = s[nt][4 + e]  * ba1[e] + bb1[e];
        s[nt][4 + e]  = v * __builtin_amdgcn_rcpf(1.f + __expf(-v));
        v = s[nt][8 + e]  * ba2[e] + bb2[e];
        s[nt][8 + e]  = v * __builtin_amdgcn_rcpf(1.f + __expf(-v));
        v = s[nt][12 + e] * ba3[e] + bb3[e];
        s[nt][12 + e] = v * __builtin_amdgcn_rcpf(1.f + __expf(-v));
      }
      #pragma unroll
      for (int e = 0; e < 8; ++e) {
        bo[nt][0][e] = (_Float16)s[nt][e];
        bo[nt][1][e] = (_Float16)s[nt][8 + e];
      }
    }
  }

  // offset MFMA: aco[mt][nt], C-in = padded bias
  f32x4 aco[2][2];
  {
    f32x4 c0 = *(const f32x4*)(pwb + lk * 4);
    f32x4 c1 = *(const f32x4*)(pwb + 16 + lk * 4);
    aco[0][0] = c0; aco[0][1] = c0;
    aco[1][0] = c1; aco[1][1] = c1;
  }
  #pragma unroll
  for (int kc = 0; kc < 2; ++kc) {
    #pragma unroll
    for (int mt = 0; mt < 2; ++mt) {
      h8 A = *(const h8*)(pwa + (mt * 2 + kc) * 512 + ln * 8);
      #pragma unroll
      for (int nt = 0; nt < 2; ++nt)
        aco[mt][nt] = __builtin_amdgcn_mfma_f32_16x16x32_f16(A, bo[nt][kc], aco[mt][nt], 0, 0, 0);
    }
  }

  // ---- dump offsets to LDS as packed f16 (within-wave; no barrier needed)
  // lane (lk,lm) holds k_off = {4lk..4lk+3} (mt0) and {16+4lk..} (mt1) for
  // pixel (qy0+nt, lm): p=2lk <- regs 0,1; p=2lk+1 <- regs 2,3; lk0: p=8.
  #pragma unroll
  for (int nt = 0; nt < 2; ++nt) {
    int px = (qy0 + nt) * 16 + lm;
    unsigned* op = (unsigned*)(off_lds + px * 48);
    h2 h01, h23;
    h01[0] = (_Float16)aco[0][nt][0];
    h01[1] = (_Float16)aco[0][nt][1];
    h23[0] = (_Float16)aco[0][nt][2];
    h23[1] = (_Float16)aco[0][nt][3];
    op[2 * lk]     = __builtin_bit_cast(unsigned, h01);
    op[2 * lk + 1] = __builtin_bit_cast(unsigned, h23);
    if (lk == 0) {
      h2 h8p;
      h8p[0] = (_Float16)aco[1][nt][0];
      h8p[1] = (_Float16)aco[1][nt][1];
      op[8] = __builtin_bit_cast(unsigned, h8p);
    }
  }
  asm volatile("s_waitcnt lgkmcnt(0)" ::: "memory");

  // ---- read back this thread's 2 pixels x 9 offset-pairs into registers
  unsigned ov[2][9];
  #pragma unroll
  for (int nt = 0; nt < 2; ++nt) {
    int px = (qy0 + nt) * 16 + lm;
    const unsigned* rp = (const unsigned*)(off_lds + px * 48);
    u32x4 r0 = *(const u32x4*)rp;
    u32x4 r1 = *(const u32x4*)(rp + 4);
    unsigned r2 = rp[8];
    ov[nt][0] = r0[0]; ov[nt][1] = r0[1]; ov[nt][2] = r0[2]; ov[nt][3] = r0[3];
    ov[nt][4] = r1[0]; ov[nt][5] = r1[1]; ov[nt][6] = r1[2]; ov[nt][7] = r1[3];
    ov[nt][8] = r2;
  }

  // ======== Phase 2: gather + MFMA ========
  f32x4 acc[4][2];     // [mt][nt]
  #pragma unroll
  for (int mt = 0; mt < 4; ++mt)
    #pragma unroll
    for (int nt = 0; nt < 2; ++nt) acc[mt][nt] = (f32x4){0.f, 0.f, 0.f, 0.f};

  const _Float16* wl = wtf2 + ln * 8;   // + (p*8 + mt*2 + kc)*512

  #pragma unroll
  for (int p = 0; p < PP; ++p) {
    h8 bfr[2][2];
    #pragma unroll
    for (int nt = 0; nt < 2; ++nt) {
      h2 hh = __builtin_bit_cast(h2, ov[nt][p]);
      float sy = (float)hh[0] + (float)(y0r + nt + p / 3 - 1);
      float sx = (float)hh[1] + (float)(tx0 + lm + p % 3 - 1);

      float y0f = floorf(sy), x0f = floorf(sx);
      float wy1 = sy - y0f, wy0 = 1.f - wy1;
      float wx1 = sx - x0f, wx0 = 1.f - wx1;
      int y0 = (int)y0f, x0i = (int)x0f;

      float w00, w01, w10, w11;
      int r00, r01, r10, r11;
      if (BORDER) {
        bool vy0 = (y0 >= 0) & (y0 < HH);
        bool vy1 = (y0 + 1 >= 0) & (y0 + 1 < HH);
        bool vx0 = (x0i >= 0) & (x0i < WW);
        bool vx1 = (x0i + 1 >= 0) & (x0i + 1 < WW);
        w00 = (vy0 && vx0) ? wy0 * wx0 : 0.f;
        w01 = (vy0 && vx1) ? wy0 * wx1 : 0.f;
        w10 = (vy1 && vx0) ? wy1 * wx0 : 0.f;
        w11 = (vy1 && vx1) ? wy1 * wx1 : 0.f;
        int iy0 = min(max(y0 - ty0 + 2, 0), 11);
        int iy1 = min(max(y0 + 1 - ty0 + 2, 0), 11);
        int ix0 = min(max(x0i - tx0 + 2, 0), 19);
        int ix1 = min(max(x0i + 1 - tx0 + 2, 0), 19);
        r00 = iy0 * 20 + ix0; r01 = iy0 * 20 + ix1;
        r10 = iy1 * 20 + ix0; r11 = iy1 * 20 + ix1;
      } else {
        w00 = wy0 * wx0; w01 = wy0 * wx1;
        w10 = wy1 * wx0; w11 = wy1 * wx1;
        int iy0 = y0 - ty0 + 2;
        int ix0 = x0i - tx0 + 2;
        r00 = iy0 * 20 + ix0; r01 = r00 + 1;
        r10 = r00 + 20;       r11 = r00 + 21;
      }

      h8 v00a = *(const h8*)(smem + r00 * 128 + (((lk    ) ^ (r00 & 7)) << 4));
      h8 v00b = *(const h8*)(smem + r00 * 128 + (((lk + 4) ^ (r00 & 7)) << 4));
      h8 v01a = *(const h8*)(smem + r01 * 128 + (((lk    ) ^ (r01 & 7)) << 4));
      h8 v01b = *(const h8*)(smem + r01 * 128 + (((lk + 4) ^ (r01 & 7)) << 4));
      h8 v10a = *(const h8*)(smem + r10 * 128 + (((lk    ) ^ (r10 & 7)) << 4));
      h8 v10b = *(const h8*)(smem + r10 * 128 + (((lk + 4) ^ (r10 & 7)) << 4));
      h8 v11a = *(const h8*)(smem + r11 * 128 + (((lk    ) ^ (r11 & 7)) << 4));
      h8 v11b = *(const h8*)(smem + r11 * 128 + (((lk + 4) ^ (r11 & 7)) << 4));

      h8 w00v = (h8)(_Float16)w00;
      h8 w01v = (h8)(_Float16)w01;
      h8 w10v = (h8)(_Float16)w10;
      h8 w11v = (h8)(_Float16)w11;
      bfr[nt][0] = v00a * w00v + v01a * w01v + v10a * w10v + v11a * w11v;
      bfr[nt][1] = v00b * w00v + v01b * w01v + v10b * w10v + v11b * w11v;
    }

    #pragma unroll
    for (int mt = 0; mt < 4; ++mt) {
      h8 a0 = *(const h8*)(wl + (p * 8 + mt * 2) * 512);
      h8 a1 = *(const h8*)(wl + (p * 8 + mt * 2 + 1) * 512);
      #pragma unroll
      for (int nt = 0; nt < 2; ++nt) {
        acc[mt][nt] = __builtin_amdgcn_mfma_f32_16x16x32_f16(a0, bfr[nt][0], acc[mt][nt], 0, 0, 0);
        acc[mt][nt] = __builtin_amdgcn_mfma_f32_16x16x32_f16(a1, bfr[nt][1], acc[mt][nt], 0, 0, 0);
      }
    }
  }

  // ---- epilogue: C/D layout col=lane&15 (pixel), row=(lane>>4)*4+reg (m)
  #pragma unroll
  for (int nt = 0; nt < 2; ++nt) {
    int pix = ((y0r + nt) << 7) + tx0 + lm;
    #pragma unroll
    for (int mt = 0; mt < 4; ++mt) {
      #pragma unroll
      for (int r = 0; r < 4; ++r) {
        int m = mt * 16 + lk * 4 + r;
        out[((size_t)b * OO + m) * HWIMG + pix] = acc[mt][nt][r] + bias[m];
      }
    }
  }
}

// ---------------------------------------------------------------------------
// Kernel 2: FUSED offsets (MFMA) + gather + MFMA, border/interior dispatch.
// LDS: 30720 halo + 6144 offsets = 36864 B -> 4 blocks/CU (147KB < 160KB).
// ---------------------------------------------------------------------------
__global__ void __launch_bounds__(256, 4)
k_main(const _Float16* __restrict__ xt,
       const float* __restrict__ dwt,
       const float* __restrict__ bnA,
       const float* __restrict__ bnB,
       const _Float16* __restrict__ pwa,
       const float* __restrict__ pwb,
       const _Float16* __restrict__ wtf2,
       const float* __restrict__ bias,
       float* __restrict__ out) {
  __shared__ __attribute__((aligned(16))) char smem[240 * 128 + 6144];
  int bid = blockIdx.x;
  int b = bid & 7, t = bid >> 3;            // XCD k <- batch k; 128 tiles/img
  int ty0 = (t >> 3) * 8, tx0 = (t & 7) * 16;
  int tid = threadIdx.x;
  const _Float16* xb = xt + (((size_t)b) << 14) * 64;

  bool border = (ty0 == 0) || (ty0 == 120) || (tx0 == 0) || (tx0 == 112);
  if (border)
    tile_body<true >(xb, dwt, bnA, bnB, pwa, pwb, wtf2, bias, out, smem, b, ty0, tx0, tid);
  else
    tile_body<false>(xb, dwt, bnA, bnB, pwa, pwb, wtf2, bias, out, smem, b, ty0, tx0, tid);
}

// ---------------------------------------------------------------------------
extern "C" void kernel_launch(void* const* d_in, const int* in_sizes, int n_in,
                              void* d_out, int out_size, void* d_ws, size_t ws_size,
                              hipStream_t stream) {
  const float* x        = (const float*)d_in[0];
  const float* dw_w     = (const float*)d_in[1];
  const float* dw_b     = (const float*)d_in[2];
  const float* bn_gamma = (const float*)d_in[3];
  const float* bn_beta  = (const float*)d_in[4];
  const float* bn_mean  = (const float*)d_in[5];
  const float* bn_var   = (const float*)d_in[6];
  const float* pw_w     = (const float*)d_in[7];
  const float* pw_b     = (const float*)d_in[8];
  const float* weight   = (const float*)d_in[9];
  const float* bias     = (const float*)d_in[10];
  float* out = (float*)d_out;

  char* ws = (char*)d_ws;
  _Float16* wtf2 = (_Float16*)ws;                              // 73728 B
  size_t o1 = (size_t)PP * OO * CC * 2;
  _Float16* xtb = (_Float16*)(ws + o1);                        // 16.8 MB
  size_t o2 = o1 + (size_t)NTOT * CC * 2;
  float* dwt = (float*)(ws + o2);                              // 2304 B
  float* bnA = (float*)(ws + o2 + 2304);                       // 256 B
  float* bnB = (float*)(ws + o2 + 2304 + 256);                 // 256 B
  _Float16* pwa = (_Float16*)(ws + o2 + 2304 + 512);           // 4096 B
  float* pwb = (float*)(ws + o2 + 2304 + 512 + 4096);          // 128 B

  k_prep<<<145, 256, 0, stream>>>(weight, dw_w, dw_b, bn_gamma, bn_beta,
                                  bn_mean, bn_var, pw_w, pw_b,
                                  wtf2, dwt, bnA, bnB, pwa, pwb);
  k_tr<<<NTOT / 64, 256, 0, stream>>>(x, xtb);
  k_main<<<NTOT / 128, 256, 0, stream>>>(xtb, dwt, bnA, bnB, pwa, pwb,
                                         wtf2, bias, out);
}

// Round 18
// 51.825 us; speedup vs baseline: 7.0089x; 1.0441x over previous
//
#include <hip/hip_runtime.h>
#include <math.h>

#define BB 8
#define CC 64
#define OO 64
#define HH 128
#define WW 128
#define PP 9
#define HWIMG 16384           // H*W per batch
#define NTOT  131072          // B*H*W
#define RSTR 144              // padded halo record stride (16B pad kills swizzle)

typedef __attribute__((ext_vector_type(8))) _Float16 h8;
typedef __attribute__((ext_vector_type(2))) _Float16 h2;
typedef __attribute__((ext_vector_type(4))) float f32x4;

// ---------------------------------------------------------------------------
// Kernel 0: prep (r16 verbatim).
// ---------------------------------------------------------------------------
__global__ void k_prep(const float* __restrict__ w,
                       const float* __restrict__ dw_w,
                       const float* __restrict__ dw_b,
                       const float* __restrict__ gamma,
                       const float* __restrict__ beta,
                       const float* __restrict__ mean,
                       const float* __restrict__ var,
                       const float* __restrict__ pw_w,
                       const float* __restrict__ pw_b,
                       _Float16* __restrict__ wtf2,
                       float* __restrict__ dwt,
                       float* __restrict__ bnA,
                       float* __restrict__ bnB,
                       _Float16* __restrict__ pwa,
                       float* __restrict__ pwb) {
  int bid = blockIdx.x, t = threadIdx.x;
  if (bid < 144) {
    int i = bid * 256 + t;
    int e  = i & 7;
    int ln = (i >> 3) & 63;
    int kc = (i >> 9) & 1;
    int mt = (i >> 10) & 3;
    int p  = i >> 12;
    int o = mt * 16 + (ln & 15);
    int c = kc * 32 + (ln >> 4) * 8 + e;
    wtf2[i] = (_Float16)w[(o * 64 + c) * 9 + p];
  } else {
    if (t < 64) {
      float A = gamma[t] * rsqrtf(var[t] + 1e-5f);
      bnA[t] = A;
      bnB[t] = (dw_b[t] - mean[t]) * A + beta[t];
    }
    if (t < 32) pwb[t] = (t < 18) ? pw_b[t] : 0.f;
    for (int i = t; i < 576; i += 256) {
      int tap = i % 9, c = i / 9;
      dwt[tap * 64 + c] = dw_w[c * 9 + tap];
    }
    for (int i = t; i < 2048; i += 256) {
      int e  = i & 7;
      int ln = (i >> 3) & 63;
      int kc = (i >> 9) & 1;
      int mt = (i >> 10) & 1;
      int ko = mt * 16 + (ln & 15);
      int c  = kc * 32 + ((ln >> 4) & 3) * 8 + e;
      pwa[i] = (ko < 18) ? (_Float16)pw_w[ko * 64 + c] : (_Float16)0.f;
    }
  }
}

// ---------------------------------------------------------------------------
// Kernel 1: x NCHW f32 -> xt[b][pix][c] f16 (NHWC) (verbatim, known good)
// ---------------------------------------------------------------------------
__global__ void __launch_bounds__(256, 4)
k_tr(const float* __restrict__ x, _Float16* __restrict__ xt) {
  __shared__ _Float16 lt[64][66];
  int bid = blockIdx.x;
  int vbid = (bid & 7) * 256 + (bid >> 3);    // XCD k <- batch k
  int tid = threadIdx.x;
  int wid = tid >> 6, ln = tid & 63;
  int b = vbid >> 8;
  int pix0 = (vbid & 255) * 64;
  const float* xbb = x + (size_t)b * CC * HWIMG;

  #pragma unroll
  for (int i = 0; i < 8; ++i) {
    int c0 = (wid * 8 + i) * 2;
    float v0 = xbb[(size_t)c0 * HWIMG + pix0 + ln];
    float v1 = xbb[(size_t)(c0 + 1) * HWIMG + pix0 + ln];
    h2 hv;
    hv[0] = (_Float16)v0;
    hv[1] = (_Float16)v1;
    *(h2*)&lt[ln][c0] = hv;
  }
  __syncthreads();

  int pq = tid >> 2, q = tid & 3;
  h8 o0, o1;
  #pragma unroll
  for (int j = 0; j < 4; ++j) {
    h2 v = *(h2*)&lt[pq][q * 16 + 2 * j];
    o0[2 * j] = v[0];
    o0[2 * j + 1] = v[1];
  }
  #pragma unroll
  for (int j = 0; j < 4; ++j) {
    h2 v = *(h2*)&lt[pq][q * 16 + 8 + 2 * j];
    o1[2 * j] = v[0];
    o1[2 * j + 1] = v[1];
  }
  _Float16* op = xt + ((size_t)((b << 14) + pix0 + pq)) * 64 + q * 16;
  *(h8*)op = o0;
  *(h8*)(op + 8) = o1;
}

// ---------------------------------------------------------------------------
// Fused tile body (r17 structure, de-swizzled LDS + one-shfl offsets).
// Halo records at stride 144B (16B pad) — plain addressing, uniform banks.
// ---------------------------------------------------------------------------
template<bool BORDER>
__device__ __forceinline__ void tile_body(
    const _Float16* __restrict__ xb,
    const float* __restrict__ dwt,
    const float* __restrict__ bnA,
    const float* __restrict__ bnB,
    const _Float16* __restrict__ pwa,
    const float* __restrict__ pwb,
    const _Float16* __restrict__ wtf2,
    const float* __restrict__ bias,
    float* __restrict__ out,
    char* smem, int b, int ty0, int tx0, int tid) {
  int wid = tid >> 6, ln = tid & 63;
  int lm = ln & 15, lk = ln >> 4;

  // ---- stage 12x20 halo records (row/col-clamped), chunk j -> slot j
  for (int ch = tid; ch < 1920; ch += 256) {
    int rec = ch >> 3, j = ch & 7;
    int ry = rec / 20, rx = rec - ry * 20;
    int yy = min(max(ty0 - 2 + ry, 0), HH - 1);
    int xx = min(max(tx0 - 2 + rx, 0), WW - 1);
    h8 v = *((const h8*)(xb + ((size_t)((yy << 7) + xx)) * 64) + j);
    *(h8*)(smem + rec * RSTR + j * 16) = v;
  }
  __syncthreads();

  int qy0 = wid * 2;
  int y0r = ty0 + qy0;

  // ======== Phase 1: offsets via MFMA ========
  float s[2][16];
  #pragma unroll
  for (int nt = 0; nt < 2; ++nt)
    #pragma unroll
    for (int e = 0; e < 16; ++e) s[nt][e] = 0.f;

  #pragma unroll
  for (int tap = 0; tap < 9; ++tap) {
    int dy = tap / 3 - 1, dx = tap % 3 - 1;
    int xc2 = tx0 + lm + dx;
    bool cok = (xc2 >= 0) & (xc2 < WW);
    const float* dwp = dwt + tap * 64;
    f32x4 d0a = *(const f32x4*)(dwp + lk * 8);
    f32x4 d0b = *(const f32x4*)(dwp + lk * 8 + 4);
    f32x4 d1a = *(const f32x4*)(dwp + 32 + lk * 8);
    f32x4 d1b = *(const f32x4*)(dwp + 32 + lk * 8 + 4);
    #pragma unroll
    for (int nt = 0; nt < 2; ++nt) {
      int rec = (qy0 + nt + dy + 2) * 20 + (lm + dx + 2);
      h8 v0 = *(const h8*)(smem + rec * RSTR + (lk    ) * 16);
      h8 v1 = *(const h8*)(smem + rec * RSTR + (lk + 4) * 16);
      if (BORDER) {
        int ry = y0r + nt + dy;
        bool ok = cok & (ry >= 0) & (ry < HH);
        if (!ok) { v0 = (h8)(_Float16)0.f; v1 = (h8)(_Float16)0.f; }
      }
      #pragma unroll
      for (int e = 0; e < 4; ++e) {
        s[nt][e]      += d0a[e] * (float)v0[e];
        s[nt][4 + e]  += d0b[e] * (float)v0[4 + e];
        s[nt][8 + e]  += d1a[e] * (float)v1[e];
        s[nt][12 + e] += d1b[e] * (float)v1[4 + e];
      }
    }
  }

  // BN + SiLU (rcp form) + pack to f16 B-frags
  h8 bo[2][2];   // [nt][kc]
  {
    f32x4 ba0 = *(const f32x4*)(bnA + lk * 8);
    f32x4 ba1 = *(const f32x4*)(bnA + lk * 8 + 4);
    f32x4 ba2 = *(const f32x4*)(bnA + 32 + lk * 8);
    f32x4 ba3 = *(const f32x4*)(bnA + 32 + lk * 8 + 4);
    f32x4 bb0 = *(const f32x4*)(bnB + lk * 8);
    f32x4 bb1 = *(const f32x4*)(bnB + lk * 8 + 4);
    f32x4 bb2 = *(const f32x4*)(bnB + 32 + lk * 8);
    f32x4 bb3 = *(const f32x4*)(bnB + 32 + lk * 8 + 4);
    #pragma unroll
    for (int nt = 0; nt < 2; ++nt) {
      #pragma unroll
      for (int e = 0; e < 4; ++e) {
        float v;
        v = s[nt][e]      * ba0[e] + bb0[e];
        s[nt][e]      = v * __builtin_amdgcn_rcpf(1.f + __expf(-v));
        v = s[nt][4 + e]  * ba1[e] + bb1[e];
        s[nt][4 + e]  = v * __builtin_amdgcn_rcpf(1.f + __expf(-v));
        v = s[nt][8 + e]  * ba2[e] + bb2[e];
        s[nt][8 + e]  = v * __builtin_amdgcn_rcpf(1.f + __expf(-v));
        v = s[nt][12 + e] * ba3[e] + bb3[e];
        s[nt][12 + e] = v * __builtin_amdgcn_rcpf(1.f + __expf(-v));
      }
      #pragma unroll
      for (int e = 0; e < 8; ++e) {
        bo[nt][0][e] = (_Float16)s[nt][e];
        bo[nt][1][e] = (_Float16)s[nt][8 + e];
      }
    }
  }

  // offset MFMA: aco[mt][nt], C-in = padded bias
  f32x4 aco[2][2];
  {
    f32x4 c0 = *(const f32x4*)(pwb + lk * 4);
    f32x4 c1 = *(const f32x4*)(pwb + 16 + lk * 4);
    aco[0][0] = c0; aco[0][1] = c0;
    aco[1][0] = c1; aco[1][1] = c1;
  }
  #pragma unroll
  for (int kc = 0; kc < 2; ++kc) {
    #pragma unroll
    for (int mt = 0; mt < 2; ++mt) {
      h8 A = *(const h8*)(pwa + (mt * 2 + kc) * 512 + ln * 8);
      #pragma unroll
      for (int nt = 0; nt < 2; ++nt)
        aco[mt][nt] = __builtin_amdgcn_mfma_f32_16x16x32_f16(A, bo[nt][kc], aco[mt][nt], 0, 0, 0);
    }
  }

  // ---- pack offsets to f16 pairs in registers; ONE shfl per (p,nt).
  // lane (lk,lm) holds k_off 4lk..4lk+3 (mt0) => pk0 serves p=2lk, pk1 p=2lk+1;
  // mt1 regs 0,1 (k=16,17) => pk2 serves p=8 (meaningful in lane group 0).
  unsigned pk0[2], pk1[2], pk2[2];
  #pragma unroll
  for (int nt = 0; nt < 2; ++nt) {
    h2 a, b2, c;
    a[0]  = (_Float16)aco[0][nt][0]; a[1]  = (_Float16)aco[0][nt][1];
    b2[0] = (_Float16)aco[0][nt][2]; b2[1] = (_Float16)aco[0][nt][3];
    c[0]  = (_Float16)aco[1][nt][0]; c[1]  = (_Float16)aco[1][nt][1];
    pk0[nt] = __builtin_bit_cast(unsigned, a);
    pk1[nt] = __builtin_bit_cast(unsigned, b2);
    pk2[nt] = __builtin_bit_cast(unsigned, c);
  }

  unsigned ov[2][9];
  #pragma unroll
  for (int nt = 0; nt < 2; ++nt) {
    ov[nt][0] = __shfl(pk0[nt], 0 * 16 + lm);
    ov[nt][1] = __shfl(pk1[nt], 0 * 16 + lm);
    ov[nt][2] = __shfl(pk0[nt], 1 * 16 + lm);
    ov[nt][3] = __shfl(pk1[nt], 1 * 16 + lm);
    ov[nt][4] = __shfl(pk0[nt], 2 * 16 + lm);
    ov[nt][5] = __shfl(pk1[nt], 2 * 16 + lm);
    ov[nt][6] = __shfl(pk0[nt], 3 * 16 + lm);
    ov[nt][7] = __shfl(pk1[nt], 3 * 16 + lm);
    ov[nt][8] = __shfl(pk2[nt], lm);
  }

  // ======== Phase 2: gather + MFMA ========
  f32x4 acc[4][2];     // [mt][nt]
  #pragma unroll
  for (int mt = 0; mt < 4; ++mt)
    #pragma unroll
    for (int nt = 0; nt < 2; ++nt) acc[mt][nt] = (f32x4){0.f, 0.f, 0.f, 0.f};

  const _Float16* wl = wtf2 + ln * 8;   // + (p*8 + mt*2 + kc)*512

  #pragma unroll
  for (int p = 0; p < PP; ++p) {
    h8 bfr[2][2];
    #pragma unroll
    for (int nt = 0; nt < 2; ++nt) {
      h2 hh = __builtin_bit_cast(h2, ov[nt][p]);
      float sy = (float)hh[0] + (float)(y0r + nt + p / 3 - 1);
      float sx = (float)hh[1] + (float)(tx0 + lm + p % 3 - 1);

      float y0f = floorf(sy), x0f = floorf(sx);
      float wy1 = sy - y0f, wy0 = 1.f - wy1;
      float wx1 = sx - x0f, wx0 = 1.f - wx1;
      int y0 = (int)y0f, x0i = (int)x0f;

      float w00, w01, w10, w11;
      int r00, r01, r10, r11;
      if (BORDER) {
        bool vy0 = (y0 >= 0) & (y0 < HH);
        bool vy1 = (y0 + 1 >= 0) & (y0 + 1 < HH);
        bool vx0 = (x0i >= 0) & (x0i < WW);
        bool vx1 = (x0i + 1 >= 0) & (x0i + 1 < WW);
        w00 = (vy0 && vx0) ? wy0 * wx0 : 0.f;
        w01 = (vy0 && vx1) ? wy0 * wx1 : 0.f;
        w10 = (vy1 && vx0) ? wy1 * wx0 : 0.f;
        w11 = (vy1 && vx1) ? wy1 * wx1 : 0.f;
        int iy0 = min(max(y0 - ty0 + 2, 0), 11);
        int iy1 = min(max(y0 + 1 - ty0 + 2, 0), 11);
        int ix0 = min(max(x0i - tx0 + 2, 0), 19);
        int ix1 = min(max(x0i + 1 - tx0 + 2, 0), 19);
        r00 = iy0 * 20 + ix0; r01 = iy0 * 20 + ix1;
        r10 = iy1 * 20 + ix0; r11 = iy1 * 20 + ix1;
      } else {
        w00 = wy0 * wx0; w01 = wy0 * wx1;
        w10 = wy1 * wx0; w11 = wy1 * wx1;
        int iy0 = y0 - ty0 + 2;
        int ix0 = x0i - tx0 + 2;
        r00 = iy0 * 20 + ix0; r01 = r00 + 1;
        r10 = r00 + 20;       r11 = r00 + 21;
      }

      h8 v00a = *(const h8*)(smem + r00 * RSTR + (lk    ) * 16);
      h8 v00b = *(const h8*)(smem + r00 * RSTR + (lk + 4) * 16);
      h8 v01a = *(const h8*)(smem + r01 * RSTR + (lk    ) * 16);
      h8 v01b = *(const h8*)(smem + r01 * RSTR + (lk + 4) * 16);
      h8 v10a = *(const h8*)(smem + r10 * RSTR + (lk    ) * 16);
      h8 v10b = *(const h8*)(smem + r10 * RSTR + (lk + 4) * 16);
      h8 v11a = *(const h8*)(smem + r11 * RSTR + (lk    ) * 16);
      h8 v11b = *(const h8*)(smem + r11 * RSTR + (lk + 4) * 16);

      h8 w00v = (h8)(_Float16)w00;
      h8 w01v = (h8)(_Float16)w01;
      h8 w10v = (h8)(_Float16)w10;
      h8 w11v = (h8)(_Float16)w11;
      bfr[nt][0] = v00a * w00v + v01a * w01v + v10a * w10v + v11a * w11v;
      bfr[nt][1] = v00b * w00v + v01b * w01v + v10b * w10v + v11b * w11v;
    }

    #pragma unroll
    for (int mt = 0; mt < 4; ++mt) {
      h8 a0 = *(const h8*)(wl + (p * 8 + mt * 2) * 512);
      h8 a1 = *(const h8*)(wl + (p * 8 + mt * 2 + 1) * 512);
      #pragma unroll
      for (int nt = 0; nt < 2; ++nt) {
        acc[mt][nt] = __builtin_amdgcn_mfma_f32_16x16x32_f16(a0, bfr[nt][0], acc[mt][nt], 0, 0, 0);
        acc[mt][nt] = __builtin_amdgcn_mfma_f32_16x16x32_f16(a1, bfr[nt][1], acc[mt][nt], 0, 0, 0);
      }
    }
  }

  // ---- epilogue: C/D layout col=lane&15 (pixel), row=(lane>>4)*4+reg (m)
  #pragma unroll
  for (int nt = 0; nt < 2; ++nt) {
    int pix = ((y0r + nt) << 7) + tx0 + lm;
    #pragma unroll
    for (int mt = 0; mt < 4; ++mt) {
      #pragma unroll
      for (int r = 0; r < 4; ++r) {
        int m = mt * 16 + lk * 4 + r;
        out[((size_t)b * OO + m) * HWIMG + pix] = acc[mt][nt][r] + bias[m];
      }
    }
  }
}

// ---------------------------------------------------------------------------
// Kernel 2: FUSED offsets (MFMA) + gather + MFMA, border/interior dispatch.
// LDS: 240 * 144 = 34560 B -> 4 blocks/CU (138 KB < 160 KB).
// ---------------------------------------------------------------------------
__global__ void __launch_bounds__(256, 4)
k_main(const _Float16* __restrict__ xt,
       const float* __restrict__ dwt,
       const float* __restrict__ bnA,
       const float* __restrict__ bnB,
       const _Float16* __restrict__ pwa,
       const float* __restrict__ pwb,
       const _Float16* __restrict__ wtf2,
       const float* __restrict__ bias,
       float* __restrict__ out) {
  __shared__ __attribute__((aligned(16))) char smem[240 * RSTR];
  int bid = blockIdx.x;
  int b = bid & 7, t = bid >> 3;            // XCD k <- batch k; 128 tiles/img
  int ty0 = (t >> 3) * 8, tx0 = (t & 7) * 16;
  int tid = threadIdx.x;
  const _Float16* xb = xt + (((size_t)b) << 14) * 64;

  bool border = (ty0 == 0) || (ty0 == 120) || (tx0 == 0) || (tx0 == 112);
  if (border)
    tile_body<true >(xb, dwt, bnA, bnB, pwa, pwb, wtf2, bias, out, smem, b, ty0, tx0, tid);
  else
    tile_body<false>(xb, dwt, bnA, bnB, pwa, pwb, wtf2, bias, out, smem, b, ty0, tx0, tid);
}

// ---------------------------------------------------------------------------
extern "C" void kernel_launch(void* const* d_in, const int* in_sizes, int n_in,
                              void* d_out, int out_size, void* d_ws, size_t ws_size,
                              hipStream_t stream) {
  const float* x        = (const float*)d_in[0];
  const float* dw_w     = (const float*)d_in[1];
  const float* dw_b     = (const float*)d_in[2];
  const float* bn_gamma = (const float*)d_in[3];
  const float* bn_beta  = (const float*)d_in[4];
  const float* bn_mean  = (const float*)d_in[5];
  const float* bn_var   = (const float*)d_in[6];
  const float* pw_w     = (const float*)d_in[7];
  const float* pw_b     = (const float*)d_in[8];
  const float* weight   = (const float*)d_in[9];
  const float* bias     = (const float*)d_in[10];
  float* out = (float*)d_out;

  char* ws = (char*)d_ws;
  _Float16* wtf2 = (_Float16*)ws;                              // 73728 B
  size_t o1 = (size_t)PP * OO * CC * 2;
  _Float16* xtb = (_Float16*)(ws + o1);                        // 16.8 MB
  size_t o2 = o1 + (size_t)NTOT * CC * 2;
  float* dwt = (float*)(ws + o2);                              // 2304 B
  float* bnA = (float*)(ws + o2 + 2304);                       // 256 B
  float* bnB = (float*)(ws + o2 + 2304 + 256);                 // 256 B
  _Float16* pwa = (_Float16*)(ws + o2 + 2304 + 512);           // 4096 B
  float* pwb = (float*)(ws + o2 + 2304 + 512 + 4096);          // 128 B

  k_prep<<<145, 256, 0, stream>>>(weight, dw_w, dw_b, bn_gamma, bn_beta,
                                  bn_mean, bn_var, pw_w, pw_b,
                                  wtf2, dwt, bnA, bnB, pwa, pwb);
  k_tr<<<NTOT / 64, 256, 0, stream>>>(x, xtb);
  k_main<<<NTOT / 128, 256, 0, stream>>>(xtb, dwt, bnA, bnB, pwa, pwb,
                                         wtf2, bias, out);
}